// Round 8
// baseline (1189.586 us; speedup 1.0000x reference)
//
#include <hip/hip_runtime.h>
#include <math.h>

#define HID 128
#define NN 128      // nodes per graph
#define NB 16       // graphs
#define BN 2048     // total nodes
#define NLAY 4
#define INF 21
#define ONF 20
#define SPAD 136    // padded LDS row stride in bf16 elems (272B: 16B-aligned, 2-way b128 — free)

// pack regions in 16B units (8 bf16 elems each)
#define U_W2   0        // 4 x 2048   (K=128, N=128)
#define U_C1   8192     // 4 x 2048
#define U_NW1  16384    // 4 x 4096   (K=256, N=128)
#define U_EW   32768    // 4 x 4096   (virtual K=128, N=256 = [ew1a|ew1b])
#define U_NW2  49152    // 4 x 2048
#define U_EOW  57344    // 1 x 2048
#define U_TOT  59392

typedef __attribute__((ext_vector_type(8))) short bf16x8;
typedef __attribute__((ext_vector_type(4))) float f32x4;

__device__ __forceinline__ float frcp(float x) {
    float r; asm("v_rcp_f32 %0, %1" : "=v"(r) : "v"(x)); return r;
}
__device__ __forceinline__ float fsilu(float v) { return v * frcp(1.f + __expf(-v)); }
__device__ __forceinline__ float fsig(float v)  { return frcp(1.f + __expf(-v)); }
__device__ __forceinline__ unsigned cvtpk_bf16(float lo, float hi) {
    unsigned r; asm("v_cvt_pk_bf16_f32 %0, %1, %2" : "=v"(r) : "v"(lo), "v"(hi)); return r;
}
__device__ __forceinline__ unsigned short f2bf(float f) {
    union { float f; unsigned u; } v; v.f = f;
    unsigned r = v.u + 0x7fffu + ((v.u >> 16) & 1u);
    return (unsigned short)(r >> 16);
}
__device__ __forceinline__ float bf2f(unsigned short u) {
    union { unsigned u; float f; } v; v.u = ((unsigned)u) << 16;
    return v.f;
}

// ---------------- pack ALL weight matrices into bf16 A-fragments of W^T ----------------
// unit u (16B = 64-lane fragment slice /8): lane l holds W[k0+j][col], j=0..7.
__global__ void k_packall(const float* __restrict__ w2, const float* __restrict__ c1,
                          const float* __restrict__ nw1, const float* __restrict__ ew1,
                          const float* __restrict__ nw2, const float* __restrict__ eow,
                          unsigned short* __restrict__ out) {
    int u = blockIdx.x * 256 + threadIdx.x;
    int l = u & 63;
    const float* src; int k0, col;
    if (u < U_C1) {                       // edge_w2, K=128
        int f = u & 2047; src = w2 + (size_t)(u >> 11) * HID * HID;
        col = (f >> 8) * 16 + (l & 15); k0 = ((f >> 6) & 3) * 32 + (l >> 4) * 8;
    } else if (u < U_NW1) {               // coord_w1, K=128
        int f = u & 2047; src = c1 + (size_t)((u - U_C1) >> 11) * HID * HID;
        col = (f >> 8) * 16 + (l & 15); k0 = ((f >> 6) & 3) * 32 + (l >> 4) * 8;
    } else if (u < U_EW) {                // node_w1, K=256
        int f = u & 4095; src = nw1 + (size_t)((u - U_NW1) >> 12) * 256 * HID;
        col = (f >> 9) * 16 + (l & 15); k0 = ((f >> 6) & 7) * 32 + (l >> 4) * 8;
    } else if (u < U_NW2) {               // edge_w1[0:256] as virtual [128 x 256]
        int f = u & 4095; src = ew1 + (size_t)((u - U_EW) >> 12) * 258 * HID;
        int c = (f >> 8) * 16 + (l & 15);             // 0..255
        col = c & 127; k0 = ((f >> 6) & 3) * 32 + (l >> 4) * 8 + (c >= 128 ? 128 : 0);
    } else if (u < U_EOW) {               // node_w2, K=128
        int f = u & 2047; src = nw2 + (size_t)((u - U_NW2) >> 11) * HID * HID;
        col = (f >> 8) * 16 + (l & 15); k0 = ((f >> 6) & 3) * 32 + (l >> 4) * 8;
    } else {                              // emb_out_w, K=128
        int f = (u - U_EOW) & 2047; src = eow;
        col = (f >> 8) * 16 + (l & 15); k0 = ((f >> 6) & 3) * 32 + (l >> 4) * 8;
    }
    unsigned short tmp[8];
#pragma unroll
    for (int j = 0; j < 8; ++j) tmp[j] = f2bf(src[(size_t)(k0 + j) * HID + col]);
    *(bf16x8*)(out + (size_t)u * 8) = *(const bf16x8*)tmp;
}

// ---------------- shared stage-C: p = h'@[ew1a|ew1b] (or h_emb = h'@eow + eob) ----------------
__device__ __forceinline__ void stageC(const unsigned short* hpt, const unsigned short* ewp,
                                       float* __restrict__ p1, float* __restrict__ p2,
                                       const float* __restrict__ eob,
                                       int n0, int lane, int wv, int last) {
    const int lc = lane & 15, lg = lane >> 4;
    bf16x8 pb[4];
#pragma unroll
    for (int kk = 0; kk < 4; ++kk)
        pb[kk] = *(const bf16x8*)&hpt[lc * SPAD + kk * 32 + lg * 8];
    if (!last) {
#pragma unroll
        for (int t4 = 0; t4 < 4; ++t4) {
            int ct = wv * 4 + t4;
            f32x4 d = (f32x4){0.f, 0.f, 0.f, 0.f};
#pragma unroll
            for (int kk = 0; kk < 4; ++kk) {
                bf16x8 a = *(const bf16x8*)(ewp + (size_t)((ct * 4 + kk) * 64 + lane) * 8);
                d = __builtin_amdgcn_mfma_f32_16x16x32_bf16(a, pb[kk], d, 0, 0, 0);
            }
            int c = ct * 16 + lg * 4;
            float* dst = (c < 128) ? (p1 + (size_t)(n0 + lc) * HID + c)
                                   : (p2 + (size_t)(n0 + lc) * HID + (c - 128));
            float4 o; o.x = d[0]; o.y = d[1]; o.z = d[2]; o.w = d[3];
            *(float4*)dst = o;
        }
    } else {
#pragma unroll
        for (int t2 = 0; t2 < 2; ++t2) {
            int ct = wv * 2 + t2;
            f32x4 d = (f32x4){0.f, 0.f, 0.f, 0.f};
#pragma unroll
            for (int kk = 0; kk < 4; ++kk) {
                bf16x8 a = *(const bf16x8*)(ewp + (size_t)((ct * 4 + kk) * 64 + lane) * 8);
                d = __builtin_amdgcn_mfma_f32_16x16x32_bf16(a, pb[kk], d, 0, 0, 0);
            }
            int c = ct * 16 + lg * 4;
            const float4 bv = *(const float4*)(eob + c);
            float4 o; o.x = d[0] + bv.x; o.y = d[1] + bv.y; o.z = d[2] + bv.z; o.w = d[3] + bv.w;
            *(float4*)(p1 + (size_t)(n0 + lc) * HID + c) = o;
        }
    }
}

// ---------------- embed + layer-0 projections (16 nodes/block, MFMA proj) ----------------
__global__ __launch_bounds__(256) void k_emb0(
    const float* __restrict__ h0, const float* __restrict__ x0,
    const float* __restrict__ wemb, const float* __restrict__ bemb,
    const unsigned short* __restrict__ ewp0,
    float* __restrict__ h, float* __restrict__ x,
    float* __restrict__ p1, float* __restrict__ p2) {
    __shared__ float hraw[16 * INF];
    __shared__ unsigned short hpt[16 * SPAD];
    const int n0 = blockIdx.x * 16;
    const int tid = threadIdx.x, lane = tid & 63, wv = tid >> 6;
    for (int t = tid; t < 16 * INF; t += 256)          // 336 > 256: strided load
        hraw[t] = h0[(size_t)n0 * INF + t];
    if (tid < 48) x[(size_t)n0 * 3 + tid] = x0[(size_t)n0 * 3 + tid];
    __syncthreads();
#pragma unroll
    for (int ot = 0; ot < 4; ++ot) {
        int idx = tid + ot * 256;          // 1024 col-pairs
        int node = idx >> 6, cp = idx & 63;
        float a0 = bemb[cp * 2], a1 = bemb[cp * 2 + 1];
#pragma unroll
        for (int k = 0; k < INF; ++k) {
            float hv = hraw[node * INF + k];
            a0 = fmaf(hv, wemb[k * HID + cp * 2], a0);
            a1 = fmaf(hv, wemb[k * HID + cp * 2 + 1], a1);
        }
        float2 o; o.x = a0; o.y = a1;
        *(float2*)(h + (size_t)(n0 + node) * HID + cp * 2) = o;
        *(unsigned*)&hpt[node * SPAD + cp * 2] = cvtpk_bf16(a0, a1);
    }
    __syncthreads();
    stageC(hpt, ewp0, p1, p2, bemb /*unused*/, n0, lane, wv, 0);
}

// ---------------- edge pipeline: one block per node i, HALF-J split for occupancy ----------------
// Two halves of 64 j-rows; each wave owns 16 rows per half. S = 64 rows -> 22.3 KB LDS
// -> 7 blocks/CU (28 waves/CU) instead of 4 (16).
__global__ __launch_bounds__(256, 7) void k_edge(
    const float* __restrict__ x, const float* __restrict__ p1g, const float* __restrict__ p2g,
    const float* __restrict__ ew1, const float* __restrict__ eb1,
    const unsigned short* __restrict__ w2p, const float* __restrict__ b2,
    const float* __restrict__ attw, const float* __restrict__ attbp,
    const unsigned short* __restrict__ c1p, const float* __restrict__ c1b, const float* __restrict__ c2,
    float* __restrict__ magg, float* __restrict__ xdel) {
    __shared__ unsigned short S[64 * SPAD];    // silu(pre) then m (ungated); rows wave-private
    __shared__ float cds[NN * 3];
    __shared__ float rad[NN];
    __shared__ float phis[NN];
    __shared__ float gatev[64];                // per-half gates, wave-private slices
    __shared__ float red[4 * HID];

    const int i = blockIdx.x;
    const int base = i & ~127;
    const int irel = i & 127;
    const int tid = threadIdx.x;
    const int lane = tid & 63;
    const int wv = tid >> 6;
    const int lc = lane & 15, lg = lane >> 4;
    const int r0 = wv * 16;                    // wave's local row base in S

    // ---- phase 0: coord diffs + radial (block-wide) ----
    const float xi0 = x[i * 3 + 0], xi1 = x[i * 3 + 1], xi2 = x[i * 3 + 2];
    if (tid < NN) {
        int j = base + tid;
        float d0 = xi0 - x[j * 3 + 0], d1 = xi1 - x[j * 3 + 1], d2 = xi2 - x[j * 3 + 2];
        cds[tid * 3 + 0] = d0; cds[tid * 3 + 1] = d1; cds[tid * 3 + 2] = d2;
        rad[tid] = d0 * d0 + d1 * d1 + d2 * d2;
    }
    __syncthreads();

    // hoisted S-build constants
    const int bl = lane & 31, bh = lane >> 5;
    const int col0 = bl * 4;
    const float4 wrv = *(const float4*)(ew1 + 256 * HID + col0);
    float4 bcv = *(const float4*)(ew1 + 257 * HID + col0);
    {
        const float4 p1v = *(const float4*)(p1g + (size_t)i * HID + col0);
        const float4 ebv = *(const float4*)(eb1 + col0);
        bcv.x += ebv.x + p1v.x; bcv.y += ebv.y + p1v.y;
        bcv.z += ebv.z + p1v.z; bcv.w += ebv.w + p1v.w;
    }
    const float attb = attbp[0];

    const int p = tid & 63;          // feature pair for m_agg
    float magg0 = 0.f, magg1 = 0.f;  // accumulated across halves

    for (int half = 0; half < 2; ++half) {
        const int jb = half * 64;

        // ---- S = silu(pre), wave-private rows [r0, r0+16) of this half ----
#pragma unroll
        for (int it = 0; it < 8; ++it) {
            int lrow = r0 + it * 2 + bh;
            int grow = jb + lrow;
            float rv = rad[grow];
            const float4 p2v = *(const float4*)(p2g + (size_t)(base + grow) * HID + col0);
            float v0 = fsilu(fmaf(rv, wrv.x, p2v.x + bcv.x));
            float v1 = fsilu(fmaf(rv, wrv.y, p2v.y + bcv.y));
            float v2 = fsilu(fmaf(rv, wrv.z, p2v.z + bcv.z));
            float v3 = fsilu(fmaf(rv, wrv.w, p2v.w + bcv.w));
            uint2 pk; pk.x = cvtpk_bf16(v0, v1); pk.y = cvtpk_bf16(v2, v3);
            *(uint2*)(S + lrow * SPAD + col0) = pk;
        }

        // ---- GEMM1: P = W2^T @ S^T (wave's 16 columns) ----
        bf16x8 bf[4];
#pragma unroll
        for (int kk = 0; kk < 4; ++kk)
            bf[kk] = *(const bf16x8*)&S[(r0 + lc) * SPAD + kk * 32 + lg * 8];
        f32x4 acc[8];
#pragma unroll
        for (int ct = 0; ct < 8; ++ct) acc[ct] = (f32x4){0.f, 0.f, 0.f, 0.f};
        __builtin_amdgcn_s_setprio(1);
#pragma unroll
        for (int ct = 0; ct < 8; ++ct)
#pragma unroll
            for (int kk = 0; kk < 4; ++kk) {
                bf16x8 a = *(const bf16x8*)(w2p + (size_t)((ct * 4 + kk) * 64 + lane) * 8);
                acc[ct] = __builtin_amdgcn_mfma_f32_16x16x32_bf16(a, bf[kk], acc[ct], 0, 0, 0);
            }
        __builtin_amdgcn_s_setprio(0);

        // ---- epilogue 1: m = silu(P + b2[c]) -> S (ungated); att partial ----
        float patt = 0.f;
#pragma unroll
        for (int ct = 0; ct < 8; ++ct) {
            const float4 b2v = *(const float4*)(b2 + ct * 16 + lg * 4);
            const float4 awv = *(const float4*)(attw + ct * 16 + lg * 4);
            f32x4 a = acc[ct];
            float m0 = fsilu(a[0] + b2v.x), m1 = fsilu(a[1] + b2v.y);
            float m2 = fsilu(a[2] + b2v.z), m3 = fsilu(a[3] + b2v.w);
            patt += m0 * awv.x + m1 * awv.y + m2 * awv.z + m3 * awv.w;
            uint2 pk; pk.x = cvtpk_bf16(m0, m1); pk.y = cvtpk_bf16(m2, m3);
            *(uint2*)(S + (r0 + lc) * SPAD + ct * 16 + lg * 4) = pk;
        }
        patt += __shfl_xor(patt, 16, 64); patt += __shfl_xor(patt, 32, 64);
        const float gv = (jb + r0 + lc == irel) ? 0.f : fsig(patt + attb);
        if (lg == 0) gatev[r0 + lc] = gv;

        // ---- GEMM2: E2 = C1^T @ m^T ----
        bf16x8 bg[4];
#pragma unroll
        for (int kk = 0; kk < 4; ++kk)
            bg[kk] = *(const bf16x8*)&S[(r0 + lc) * SPAD + kk * 32 + lg * 8];
        f32x4 acc2[8];
#pragma unroll
        for (int ct = 0; ct < 8; ++ct) acc2[ct] = (f32x4){0.f, 0.f, 0.f, 0.f};
        __builtin_amdgcn_s_setprio(1);
#pragma unroll
        for (int ct = 0; ct < 8; ++ct)
#pragma unroll
            for (int kk = 0; kk < 4; ++kk) {
                bf16x8 a = *(const bf16x8*)(c1p + (size_t)((ct * 4 + kk) * 64 + lane) * 8);
                acc2[ct] = __builtin_amdgcn_mfma_f32_16x16x32_bf16(a, bg[kk], acc2[ct], 0, 0, 0);
            }
        __builtin_amdgcn_s_setprio(0);

        // ---- phi[j] = sum_c silu(g_j*E2 + c1b)*c2 ----
        float pp = 0.f;
#pragma unroll
        for (int ct = 0; ct < 8; ++ct) {
            const float4 cbv = *(const float4*)(c1b + ct * 16 + lg * 4);
            const float4 cwv = *(const float4*)(c2 + ct * 16 + lg * 4);
            f32x4 a = acc2[ct];
            pp += fsilu(fmaf(gv, a[0], cbv.x)) * cwv.x + fsilu(fmaf(gv, a[1], cbv.y)) * cwv.y +
                  fsilu(fmaf(gv, a[2], cbv.z)) * cwv.z + fsilu(fmaf(gv, a[3], cbv.w)) * cwv.w;
        }
        pp += __shfl_xor(pp, 16, 64); pp += __shfl_xor(pp, 32, 64);
        if (lg == 0) phis[jb + r0 + lc] = pp;

        // ---- m_agg partial: wave's 16 rows of this half ----
#pragma unroll
        for (int q = 0; q < 16; ++q) {
            float g = gatev[r0 + q];
            unsigned u = *(const unsigned*)(S + (r0 + q) * SPAD + p * 2);
            magg0 = fmaf(g, bf2f((unsigned short)(u & 0xffffu)), magg0);
            magg1 = fmaf(g, bf2f((unsigned short)(u >> 16)), magg1);
        }
    }

    {
        float2 pr; pr.x = magg0; pr.y = magg1;
        *(float2*)(red + wv * HID + p * 2) = pr;
    }
    __syncthreads();   // B1: phis + red complete

    if (tid < NN) {
        float ph = phis[tid];
        cds[tid * 3 + 0] *= ph; cds[tid * 3 + 1] *= ph; cds[tid * 3 + 2] *= ph;
    }
    if (tid < HID)
        magg[(size_t)i * HID + tid] = red[tid] + red[HID + tid] + red[2 * HID + tid] + red[3 * HID + tid];
    __syncthreads();   // B2: cds scaled

    if (tid < 192) {
        const int a = tid >> 6, ln = tid & 63;
        float v = cds[ln * 3 + a] + cds[(ln + 64) * 3 + a];
#pragma unroll
        for (int off = 1; off <= 32; off <<= 1) v += __shfl_xor(v, off, 64);
        if (ln == 0) xdel[i * 3 + a] = v * (1.f / 127.f);
    }
}

// ---------------- node path via MFMA: 16 nodes/block, 128 blocks ----------------
__global__ __launch_bounds__(256) void k_node2(
    float* __restrict__ h, float* __restrict__ x,
    const float* __restrict__ magg, const float* __restrict__ xdel,
    const unsigned short* __restrict__ nw1p, const float* __restrict__ nb1,
    const unsigned short* __restrict__ nw2p, const float* __restrict__ nb2,
    const unsigned short* __restrict__ ewp, const float* __restrict__ eob,
    float* __restrict__ p1, float* __restrict__ p2, int last) {
    __shared__ unsigned short hm[16 * 264];   // [node][h(128)|magg(128)] bf16
    __shared__ float hf[16 * 132];            // h fp32 tile (padded)
    __shared__ unsigned short dht[16 * SPAD];
    __shared__ unsigned short hpt[16 * SPAD];

    const int n0 = blockIdx.x * 16;
    const int tid = threadIdx.x, lane = tid & 63, wv = tid >> 6;
    const int lc = lane & 15, lg = lane >> 4;

    {
        int node = tid >> 4, seg = tid & 15;
        const float* srcp = (seg < 8) ? (h + (size_t)(n0 + node) * HID + seg * 16)
                                      : (magg + (size_t)(n0 + node) * HID + (seg - 8) * 16);
        float4 v0 = ((const float4*)srcp)[0];
        float4 v1 = ((const float4*)srcp)[1];
        float4 v2 = ((const float4*)srcp)[2];
        float4 v3 = ((const float4*)srcp)[3];
        uint4 q0; q0.x = cvtpk_bf16(v0.x, v0.y); q0.y = cvtpk_bf16(v0.z, v0.w);
                  q0.z = cvtpk_bf16(v1.x, v1.y); q0.w = cvtpk_bf16(v1.z, v1.w);
        uint4 q1; q1.x = cvtpk_bf16(v2.x, v2.y); q1.y = cvtpk_bf16(v2.z, v2.w);
                  q1.z = cvtpk_bf16(v3.x, v3.y); q1.w = cvtpk_bf16(v3.z, v3.w);
        *(uint4*)&hm[node * 264 + seg * 16] = q0;
        *(uint4*)&hm[node * 264 + seg * 16 + 8] = q1;
        if (seg < 8) {
            float* dst = &hf[node * 132 + seg * 16];
            ((float4*)dst)[0] = v0; ((float4*)dst)[1] = v1;
            ((float4*)dst)[2] = v2; ((float4*)dst)[3] = v3;
        }
    }
    __syncthreads();

    // ---- stage A: dh = silu([h|magg]@nw1 + nb1) ----
    bf16x8 bb[8];
#pragma unroll
    for (int kk = 0; kk < 8; ++kk)
        bb[kk] = *(const bf16x8*)&hm[lc * 264 + kk * 32 + lg * 8];
    f32x4 da[2] = {(f32x4){0.f,0.f,0.f,0.f}, (f32x4){0.f,0.f,0.f,0.f}};
#pragma unroll
    for (int t2 = 0; t2 < 2; ++t2) {
        int ct = wv * 2 + t2;
#pragma unroll
        for (int kk = 0; kk < 8; ++kk) {
            bf16x8 a = *(const bf16x8*)(nw1p + (size_t)((ct * 8 + kk) * 64 + lane) * 8);
            da[t2] = __builtin_amdgcn_mfma_f32_16x16x32_bf16(a, bb[kk], da[t2], 0, 0, 0);
        }
    }
#pragma unroll
    for (int t2 = 0; t2 < 2; ++t2) {
        int ct = wv * 2 + t2;
        const float4 bv = *(const float4*)(nb1 + ct * 16 + lg * 4);
        float m0 = fsilu(da[t2][0] + bv.x), m1 = fsilu(da[t2][1] + bv.y);
        float m2 = fsilu(da[t2][2] + bv.z), m3 = fsilu(da[t2][3] + bv.w);
        uint2 pk; pk.x = cvtpk_bf16(m0, m1); pk.y = cvtpk_bf16(m2, m3);
        *(uint2*)&dht[lc * SPAD + ct * 16 + lg * 4] = pk;
    }
    __syncthreads();

    // ---- stage B: h' = h + dh@nw2 + nb2 ----
    bf16x8 db[4];
#pragma unroll
    for (int kk = 0; kk < 4; ++kk)
        db[kk] = *(const bf16x8*)&dht[lc * SPAD + kk * 32 + lg * 8];
    f32x4 hb[2] = {(f32x4){0.f,0.f,0.f,0.f}, (f32x4){0.f,0.f,0.f,0.f}};
#pragma unroll
    for (int t2 = 0; t2 < 2; ++t2) {
        int ct = wv * 2 + t2;
#pragma unroll
        for (int kk = 0; kk < 4; ++kk) {
            bf16x8 a = *(const bf16x8*)(nw2p + (size_t)((ct * 4 + kk) * 64 + lane) * 8);
            hb[t2] = __builtin_amdgcn_mfma_f32_16x16x32_bf16(a, db[kk], hb[t2], 0, 0, 0);
        }
    }
#pragma unroll
    for (int t2 = 0; t2 < 2; ++t2) {
        int ct = wv * 2 + t2;
        const float4 bv = *(const float4*)(nb2 + ct * 16 + lg * 4);
        const float4 hv = *(const float4*)&hf[lc * 132 + ct * 16 + lg * 4];
        float o0 = hv.x + hb[t2][0] + bv.x, o1 = hv.y + hb[t2][1] + bv.y;
        float o2 = hv.z + hb[t2][2] + bv.z, o3 = hv.w + hb[t2][3] + bv.w;
        float4 o; o.x = o0; o.y = o1; o.z = o2; o.w = o3;
        *(float4*)(h + (size_t)(n0 + lc) * HID + ct * 16 + lg * 4) = o;
        uint2 pk; pk.x = cvtpk_bf16(o0, o1); pk.y = cvtpk_bf16(o2, o3);
        *(uint2*)&hpt[lc * SPAD + ct * 16 + lg * 4] = pk;
    }
    if (tid < 48) {
        int n = tid / 3, a = tid % 3;
        x[(size_t)(n0 + n) * 3 + a] += xdel[(size_t)(n0 + n) * 3 + a];
    }
    __syncthreads();

    // ---- stage C ----
    stageC(hpt, ewp, p1, p2, eob, n0, lane, wv, last);
}

// ---------------- per-graph mean pool + head MLP ----------------
__global__ void k_poolhead(const float* __restrict__ he,
                           const float* __restrict__ w1, const float* __restrict__ b1,
                           const float* __restrict__ w2, const float* __restrict__ b2,
                           float* __restrict__ out) {
    __shared__ float hp[HID], rs[HID];
    int gph = blockIdx.x, t = threadIdx.x;
    float s = 0.f;
    for (int j = 0; j < NN; ++j) s += he[(size_t)(gph * NN + j) * HID + t];
    hp[t] = s * (1.f / 128.f);
    __syncthreads();
    float acc = b1[t];
#pragma unroll 4
    for (int k = 0; k < HID; ++k) acc += hp[k] * w1[k * HID + t];
    rs[t] = fmaxf(acc, 0.f);
    __syncthreads();
    if (t < ONF) {
        float a = b2[t];
        for (int k = 0; k < HID; ++k) a += rs[k] * w2[k * ONF + t];
        out[gph * ONF + t] = a;
    }
}

extern "C" void kernel_launch(void* const* d_in, const int* in_sizes, int n_in,
                              void* d_out, int out_size, void* d_ws, size_t ws_size,
                              hipStream_t stream) {
    const float* h0        = (const float*)d_in[0];
    const float* x0        = (const float*)d_in[1];
    const float* emb_in_w  = (const float*)d_in[2];
    const float* emb_in_b  = (const float*)d_in[3];
    const float* edge_w1   = (const float*)d_in[4];
    const float* edge_b1   = (const float*)d_in[5];
    const float* edge_w2   = (const float*)d_in[6];
    const float* edge_b2   = (const float*)d_in[7];
    const float* att_w     = (const float*)d_in[8];
    const float* att_b     = (const float*)d_in[9];
    const float* node_w1   = (const float*)d_in[10];
    const float* node_b1   = (const float*)d_in[11];
    const float* node_w2   = (const float*)d_in[12];
    const float* node_b2   = (const float*)d_in[13];
    const float* coord_w1  = (const float*)d_in[14];
    const float* coord_b1  = (const float*)d_in[15];
    const float* coord_w2  = (const float*)d_in[16];
    const float* emb_out_w = (const float*)d_in[17];
    const float* emb_out_b = (const float*)d_in[18];
    const float* head_w1   = (const float*)d_in[19];
    const float* head_b1   = (const float*)d_in[20];
    const float* head_w2   = (const float*)d_in[21];
    const float* head_b2   = (const float*)d_in[22];

    float* ws    = (float*)d_ws;
    float* h_cur = ws;                   // BN*HID
    float* p1    = h_cur + BN * HID;     // BN*HID (h_emb at the end)
    float* p2    = p1 + BN * HID;        // BN*HID
    float* magg  = p2 + BN * HID;        // BN*HID
    float* xc    = magg + BN * HID;      // BN*3
    float* xdel  = xc + BN * 3;          // BN*3
    unsigned short* wpack = (unsigned short*)(xdel + BN * 3);  // U_TOT * 8 bf16

    k_packall<<<U_TOT / 256, 256, 0, stream>>>(edge_w2, coord_w1, node_w1, edge_w1,
                                               node_w2, emb_out_w, wpack);
    k_emb0<<<BN / 16, 256, 0, stream>>>(h0, x0, emb_in_w, emb_in_b,
                                        wpack + (size_t)U_EW * 8, h_cur, xc, p1, p2);
    for (int l = 0; l < NLAY; ++l) {
        const int last = (l == NLAY - 1);
        k_edge<<<BN, 256, 0, stream>>>(xc, p1, p2,
            edge_w1 + (size_t)l * 258 * HID, edge_b1 + l * HID,
            wpack + (size_t)(U_W2 + l * 2048) * 8, edge_b2 + l * HID,
            att_w + l * HID, att_b + l,
            wpack + (size_t)(U_C1 + l * 2048) * 8, coord_b1 + l * HID, coord_w2 + l * HID,
            magg, xdel);
        k_node2<<<BN / 16, 256, 0, stream>>>(h_cur, xc, magg, xdel,
            wpack + (size_t)(U_NW1 + l * 4096) * 8, node_b1 + l * HID,
            wpack + (size_t)(U_NW2 + l * 2048) * 8, node_b2 + l * HID,
            last ? wpack + (size_t)U_EOW * 8 : wpack + (size_t)(U_EW + (l + 1) * 4096) * 8,
            emb_out_b, p1, p2, last);
    }
    k_poolhead<<<NB, HID, 0, stream>>>(p1, head_w1, head_b1, head_w2, head_b2, (float*)d_out);
}

// Round 9
// 892.129 us; speedup vs baseline: 1.3334x; 1.3334x over previous
//
#include <hip/hip_runtime.h>
#include <math.h>

#define HID 128
#define NN 128      // nodes per graph
#define NB 16       // graphs
#define BN 2048     // total nodes
#define NLAY 4
#define INF 21
#define ONF 20
#define SPAD 136    // padded LDS row stride in bf16 elems (272B: 16B-aligned, 2-way b128 — free)

// pack regions in 16B units (8 bf16 elems each)
#define U_W2   0        // 4 x 2048   (K=128, N=128)
#define U_C1   8192     // 4 x 2048
#define U_NW1  16384    // 4 x 4096   (K=256, N=128)
#define U_EW   32768    // 4 x 4096   (virtual K=128, N=256 = [ew1a|ew1b])
#define U_NW2  49152    // 4 x 2048
#define U_EOW  57344    // 1 x 2048
#define U_TOT  59392

typedef __attribute__((ext_vector_type(8))) short bf16x8;
typedef __attribute__((ext_vector_type(4))) float f32x4;

__device__ __forceinline__ float frcp(float x) {
    float r; asm("v_rcp_f32 %0, %1" : "=v"(r) : "v"(x)); return r;
}
__device__ __forceinline__ float fsilu(float v) { return v * frcp(1.f + __expf(-v)); }
__device__ __forceinline__ float fsig(float v)  { return frcp(1.f + __expf(-v)); }
__device__ __forceinline__ unsigned cvtpk_bf16(float lo, float hi) {
    unsigned r; asm("v_cvt_pk_bf16_f32 %0, %1, %2" : "=v"(r) : "v"(lo), "v"(hi)); return r;
}
__device__ __forceinline__ unsigned short f2bf(float f) {
    union { float f; unsigned u; } v; v.f = f;
    unsigned r = v.u + 0x7fffu + ((v.u >> 16) & 1u);
    return (unsigned short)(r >> 16);
}
__device__ __forceinline__ float bf2f(unsigned short u) {
    union { unsigned u; float f; } v; v.u = ((unsigned)u) << 16;
    return v.f;
}

// ---------------- pack ALL weight matrices into bf16 A-fragments of W^T ----------------
// unit u (16B = 64-lane fragment slice /8): lane l holds W[k0+j][col], j=0..7.
__global__ void k_packall(const float* __restrict__ w2, const float* __restrict__ c1,
                          const float* __restrict__ nw1, const float* __restrict__ ew1,
                          const float* __restrict__ nw2, const float* __restrict__ eow,
                          unsigned short* __restrict__ out) {
    int u = blockIdx.x * 256 + threadIdx.x;
    int l = u & 63;
    const float* src; int k0, col;
    if (u < U_C1) {                       // edge_w2, K=128
        int f = u & 2047; src = w2 + (size_t)(u >> 11) * HID * HID;
        col = (f >> 8) * 16 + (l & 15); k0 = ((f >> 6) & 3) * 32 + (l >> 4) * 8;
    } else if (u < U_NW1) {               // coord_w1, K=128
        int f = u & 2047; src = c1 + (size_t)((u - U_C1) >> 11) * HID * HID;
        col = (f >> 8) * 16 + (l & 15); k0 = ((f >> 6) & 3) * 32 + (l >> 4) * 8;
    } else if (u < U_EW) {                // node_w1, K=256
        int f = u & 4095; src = nw1 + (size_t)((u - U_NW1) >> 12) * 256 * HID;
        col = (f >> 9) * 16 + (l & 15); k0 = ((f >> 6) & 7) * 32 + (l >> 4) * 8;
    } else if (u < U_NW2) {               // edge_w1[0:256] as virtual [128 x 256]
        int f = u & 4095; src = ew1 + (size_t)((u - U_EW) >> 12) * 258 * HID;
        int c = (f >> 8) * 16 + (l & 15);             // 0..255
        col = c & 127; k0 = ((f >> 6) & 3) * 32 + (l >> 4) * 8 + (c >= 128 ? 128 : 0);
    } else if (u < U_EOW) {               // node_w2, K=128
        int f = u & 2047; src = nw2 + (size_t)((u - U_NW2) >> 11) * HID * HID;
        col = (f >> 8) * 16 + (l & 15); k0 = ((f >> 6) & 3) * 32 + (l >> 4) * 8;
    } else {                              // emb_out_w, K=128
        int f = (u - U_EOW) & 2047; src = eow;
        col = (f >> 8) * 16 + (l & 15); k0 = ((f >> 6) & 3) * 32 + (l >> 4) * 8;
    }
    unsigned short tmp[8];
#pragma unroll
    for (int j = 0; j < 8; ++j) tmp[j] = f2bf(src[(size_t)(k0 + j) * HID + col]);
    *(bf16x8*)(out + (size_t)u * 8) = *(const bf16x8*)tmp;
}

// ---------------- shared stage-C: p = h'@[ew1a|ew1b] (or h_emb = h'@eow + eob) ----------------
__device__ __forceinline__ void stageC(const unsigned short* hpt, const unsigned short* ewp,
                                       float* __restrict__ p1, float* __restrict__ p2,
                                       const float* __restrict__ eob,
                                       int n0, int lane, int wv, int last) {
    const int lc = lane & 15, lg = lane >> 4;
    bf16x8 pb[4];
#pragma unroll
    for (int kk = 0; kk < 4; ++kk)
        pb[kk] = *(const bf16x8*)&hpt[lc * SPAD + kk * 32 + lg * 8];
    if (!last) {
#pragma unroll
        for (int t4 = 0; t4 < 4; ++t4) {
            int ct = wv * 4 + t4;
            f32x4 d = (f32x4){0.f, 0.f, 0.f, 0.f};
#pragma unroll
            for (int kk = 0; kk < 4; ++kk) {
                bf16x8 a = *(const bf16x8*)(ewp + (size_t)((ct * 4 + kk) * 64 + lane) * 8);
                d = __builtin_amdgcn_mfma_f32_16x16x32_bf16(a, pb[kk], d, 0, 0, 0);
            }
            int c = ct * 16 + lg * 4;
            float* dst = (c < 128) ? (p1 + (size_t)(n0 + lc) * HID + c)
                                   : (p2 + (size_t)(n0 + lc) * HID + (c - 128));
            float4 o; o.x = d[0]; o.y = d[1]; o.z = d[2]; o.w = d[3];
            *(float4*)dst = o;
        }
    } else {
#pragma unroll
        for (int t2 = 0; t2 < 2; ++t2) {
            int ct = wv * 2 + t2;
            f32x4 d = (f32x4){0.f, 0.f, 0.f, 0.f};
#pragma unroll
            for (int kk = 0; kk < 4; ++kk) {
                bf16x8 a = *(const bf16x8*)(ewp + (size_t)((ct * 4 + kk) * 64 + lane) * 8);
                d = __builtin_amdgcn_mfma_f32_16x16x32_bf16(a, pb[kk], d, 0, 0, 0);
            }
            int c = ct * 16 + lg * 4;
            const float4 bv = *(const float4*)(eob + c);
            float4 o; o.x = d[0] + bv.x; o.y = d[1] + bv.y; o.z = d[2] + bv.z; o.w = d[3] + bv.w;
            *(float4*)(p1 + (size_t)(n0 + lc) * HID + c) = o;
        }
    }
}

// ---------------- embed + layer-0 projections (16 nodes/block, MFMA proj) ----------------
__global__ __launch_bounds__(256) void k_emb0(
    const float* __restrict__ h0, const float* __restrict__ x0,
    const float* __restrict__ wemb, const float* __restrict__ bemb,
    const unsigned short* __restrict__ ewp0,
    float* __restrict__ h, float* __restrict__ x,
    float* __restrict__ p1, float* __restrict__ p2) {
    __shared__ float hraw[16 * INF];
    __shared__ unsigned short hpt[16 * SPAD];
    const int n0 = blockIdx.x * 16;
    const int tid = threadIdx.x, lane = tid & 63, wv = tid >> 6;
    for (int t = tid; t < 16 * INF; t += 256)          // 336 > 256: strided load
        hraw[t] = h0[(size_t)n0 * INF + t];
    if (tid < 48) x[(size_t)n0 * 3 + tid] = x0[(size_t)n0 * 3 + tid];
    __syncthreads();
#pragma unroll
    for (int ot = 0; ot < 4; ++ot) {
        int idx = tid + ot * 256;          // 1024 col-pairs
        int node = idx >> 6, cp = idx & 63;
        float a0 = bemb[cp * 2], a1 = bemb[cp * 2 + 1];
#pragma unroll
        for (int k = 0; k < INF; ++k) {
            float hv = hraw[node * INF + k];
            a0 = fmaf(hv, wemb[k * HID + cp * 2], a0);
            a1 = fmaf(hv, wemb[k * HID + cp * 2 + 1], a1);
        }
        float2 o; o.x = a0; o.y = a1;
        *(float2*)(h + (size_t)(n0 + node) * HID + cp * 2) = o;
        *(unsigned*)&hpt[node * SPAD + cp * 2] = cvtpk_bf16(a0, a1);
    }
    __syncthreads();
    stageC(hpt, ewp0, p1, p2, bemb /*unused*/, n0, lane, wv, 0);
}

// ---------------- edge pipeline: one block per node i, HALF-J split for occupancy ----------------
// Two halves of 64 j-rows; each wave owns 16 rows per half. S = 64 rows -> 22.3 KB LDS.
// launch_bounds(256,6): VGPR cap ~85 — (256,7) forced 36 VGPR and spilled (round-8 regression).
__global__ __launch_bounds__(256, 6) void k_edge(
    const float* __restrict__ x, const float* __restrict__ p1g, const float* __restrict__ p2g,
    const float* __restrict__ ew1, const float* __restrict__ eb1,
    const unsigned short* __restrict__ w2p, const float* __restrict__ b2,
    const float* __restrict__ attw, const float* __restrict__ attbp,
    const unsigned short* __restrict__ c1p, const float* __restrict__ c1b, const float* __restrict__ c2,
    float* __restrict__ magg, float* __restrict__ xdel) {
    __shared__ unsigned short S[64 * SPAD];    // silu(pre) then m (ungated); rows wave-private
    __shared__ float cds[NN * 3];
    __shared__ float rad[NN];
    __shared__ float phis[NN];
    __shared__ float gatev[64];                // per-half gates, wave-private slices
    __shared__ float red[4 * HID];

    const int i = blockIdx.x;
    const int base = i & ~127;
    const int irel = i & 127;
    const int tid = threadIdx.x;
    const int lane = tid & 63;
    const int wv = tid >> 6;
    const int lc = lane & 15, lg = lane >> 4;
    const int r0 = wv * 16;                    // wave's local row base in S

    // ---- phase 0: coord diffs + radial (block-wide) ----
    const float xi0 = x[i * 3 + 0], xi1 = x[i * 3 + 1], xi2 = x[i * 3 + 2];
    if (tid < NN) {
        int j = base + tid;
        float d0 = xi0 - x[j * 3 + 0], d1 = xi1 - x[j * 3 + 1], d2 = xi2 - x[j * 3 + 2];
        cds[tid * 3 + 0] = d0; cds[tid * 3 + 1] = d1; cds[tid * 3 + 2] = d2;
        rad[tid] = d0 * d0 + d1 * d1 + d2 * d2;
    }
    __syncthreads();

    // hoisted S-build constants
    const int bl = lane & 31, bh = lane >> 5;
    const int col0 = bl * 4;
    const float4 wrv = *(const float4*)(ew1 + 256 * HID + col0);
    float4 bcv = *(const float4*)(ew1 + 257 * HID + col0);
    {
        const float4 p1v = *(const float4*)(p1g + (size_t)i * HID + col0);
        const float4 ebv = *(const float4*)(eb1 + col0);
        bcv.x += ebv.x + p1v.x; bcv.y += ebv.y + p1v.y;
        bcv.z += ebv.z + p1v.z; bcv.w += ebv.w + p1v.w;
    }
    const float attb = attbp[0];

    const int p = tid & 63;          // feature pair for m_agg
    float magg0 = 0.f, magg1 = 0.f;  // accumulated across halves

    for (int half = 0; half < 2; ++half) {
        const int jb = half * 64;

        // ---- S = silu(pre), wave-private rows [r0, r0+16) of this half ----
#pragma unroll
        for (int it = 0; it < 8; ++it) {
            int lrow = r0 + it * 2 + bh;
            int grow = jb + lrow;
            float rv = rad[grow];
            const float4 p2v = *(const float4*)(p2g + (size_t)(base + grow) * HID + col0);
            float v0 = fsilu(fmaf(rv, wrv.x, p2v.x + bcv.x));
            float v1 = fsilu(fmaf(rv, wrv.y, p2v.y + bcv.y));
            float v2 = fsilu(fmaf(rv, wrv.z, p2v.z + bcv.z));
            float v3 = fsilu(fmaf(rv, wrv.w, p2v.w + bcv.w));
            uint2 pk; pk.x = cvtpk_bf16(v0, v1); pk.y = cvtpk_bf16(v2, v3);
            *(uint2*)(S + lrow * SPAD + col0) = pk;
        }

        // ---- GEMM1: P = W2^T @ S^T (wave's 16 columns) ----
        bf16x8 bf[4];
#pragma unroll
        for (int kk = 0; kk < 4; ++kk)
            bf[kk] = *(const bf16x8*)&S[(r0 + lc) * SPAD + kk * 32 + lg * 8];
        f32x4 acc[8];
#pragma unroll
        for (int ct = 0; ct < 8; ++ct) acc[ct] = (f32x4){0.f, 0.f, 0.f, 0.f};
        __builtin_amdgcn_s_setprio(1);
#pragma unroll
        for (int ct = 0; ct < 8; ++ct)
#pragma unroll
            for (int kk = 0; kk < 4; ++kk) {
                bf16x8 a = *(const bf16x8*)(w2p + (size_t)((ct * 4 + kk) * 64 + lane) * 8);
                acc[ct] = __builtin_amdgcn_mfma_f32_16x16x32_bf16(a, bf[kk], acc[ct], 0, 0, 0);
            }
        __builtin_amdgcn_s_setprio(0);

        // ---- epilogue 1: m = silu(P + b2[c]) -> S (ungated); att partial ----
        float patt = 0.f;
#pragma unroll
        for (int ct = 0; ct < 8; ++ct) {
            const float4 b2v = *(const float4*)(b2 + ct * 16 + lg * 4);
            const float4 awv = *(const float4*)(attw + ct * 16 + lg * 4);
            f32x4 a = acc[ct];
            float m0 = fsilu(a[0] + b2v.x), m1 = fsilu(a[1] + b2v.y);
            float m2 = fsilu(a[2] + b2v.z), m3 = fsilu(a[3] + b2v.w);
            patt += m0 * awv.x + m1 * awv.y + m2 * awv.z + m3 * awv.w;
            uint2 pk; pk.x = cvtpk_bf16(m0, m1); pk.y = cvtpk_bf16(m2, m3);
            *(uint2*)(S + (r0 + lc) * SPAD + ct * 16 + lg * 4) = pk;
        }
        patt += __shfl_xor(patt, 16, 64); patt += __shfl_xor(patt, 32, 64);
        const float gv = (jb + r0 + lc == irel) ? 0.f : fsig(patt + attb);
        if (lg == 0) gatev[r0 + lc] = gv;

        // ---- GEMM2: E2 = C1^T @ m^T ----
        bf16x8 bg[4];
#pragma unroll
        for (int kk = 0; kk < 4; ++kk)
            bg[kk] = *(const bf16x8*)&S[(r0 + lc) * SPAD + kk * 32 + lg * 8];
        f32x4 acc2[8];
#pragma unroll
        for (int ct = 0; ct < 8; ++ct) acc2[ct] = (f32x4){0.f, 0.f, 0.f, 0.f};
        __builtin_amdgcn_s_setprio(1);
#pragma unroll
        for (int ct = 0; ct < 8; ++ct)
#pragma unroll
            for (int kk = 0; kk < 4; ++kk) {
                bf16x8 a = *(const bf16x8*)(c1p + (size_t)((ct * 4 + kk) * 64 + lane) * 8);
                acc2[ct] = __builtin_amdgcn_mfma_f32_16x16x32_bf16(a, bg[kk], acc2[ct], 0, 0, 0);
            }
        __builtin_amdgcn_s_setprio(0);

        // ---- phi[j] = sum_c silu(g_j*E2 + c1b)*c2 ----
        float pp = 0.f;
#pragma unroll
        for (int ct = 0; ct < 8; ++ct) {
            const float4 cbv = *(const float4*)(c1b + ct * 16 + lg * 4);
            const float4 cwv = *(const float4*)(c2 + ct * 16 + lg * 4);
            f32x4 a = acc2[ct];
            pp += fsilu(fmaf(gv, a[0], cbv.x)) * cwv.x + fsilu(fmaf(gv, a[1], cbv.y)) * cwv.y +
                  fsilu(fmaf(gv, a[2], cbv.z)) * cwv.z + fsilu(fmaf(gv, a[3], cbv.w)) * cwv.w;
        }
        pp += __shfl_xor(pp, 16, 64); pp += __shfl_xor(pp, 32, 64);
        if (lg == 0) phis[jb + r0 + lc] = pp;

        // ---- m_agg partial: wave's 16 rows of this half ----
#pragma unroll
        for (int q = 0; q < 16; ++q) {
            float g = gatev[r0 + q];
            unsigned u = *(const unsigned*)(S + (r0 + q) * SPAD + p * 2);
            magg0 = fmaf(g, bf2f((unsigned short)(u & 0xffffu)), magg0);
            magg1 = fmaf(g, bf2f((unsigned short)(u >> 16)), magg1);
        }
    }

    {
        float2 pr; pr.x = magg0; pr.y = magg1;
        *(float2*)(red + wv * HID + p * 2) = pr;
    }
    __syncthreads();   // B1: phis + red complete

    if (tid < NN) {
        float ph = phis[tid];
        cds[tid * 3 + 0] *= ph; cds[tid * 3 + 1] *= ph; cds[tid * 3 + 2] *= ph;
    }
    if (tid < HID)
        magg[(size_t)i * HID + tid] = red[tid] + red[HID + tid] + red[2 * HID + tid] + red[3 * HID + tid];
    __syncthreads();   // B2: cds scaled

    if (tid < 192) {
        const int a = tid >> 6, ln = tid & 63;
        float v = cds[ln * 3 + a] + cds[(ln + 64) * 3 + a];
#pragma unroll
        for (int off = 1; off <= 32; off <<= 1) v += __shfl_xor(v, off, 64);
        if (ln == 0) xdel[i * 3 + a] = v * (1.f / 127.f);
    }
}

// ---------------- node path via MFMA: 16 nodes/block, 128 blocks ----------------
__global__ __launch_bounds__(256) void k_node2(
    float* __restrict__ h, float* __restrict__ x,
    const float* __restrict__ magg, const float* __restrict__ xdel,
    const unsigned short* __restrict__ nw1p, const float* __restrict__ nb1,
    const unsigned short* __restrict__ nw2p, const float* __restrict__ nb2,
    const unsigned short* __restrict__ ewp, const float* __restrict__ eob,
    float* __restrict__ p1, float* __restrict__ p2, int last) {
    __shared__ unsigned short hm[16 * 264];   // [node][h(128)|magg(128)] bf16
    __shared__ float hf[16 * 132];            // h fp32 tile (padded)
    __shared__ unsigned short dht[16 * SPAD];
    __shared__ unsigned short hpt[16 * SPAD];

    const int n0 = blockIdx.x * 16;
    const int tid = threadIdx.x, lane = tid & 63, wv = tid >> 6;
    const int lc = lane & 15, lg = lane >> 4;

    {
        int node = tid >> 4, seg = tid & 15;
        const float* srcp = (seg < 8) ? (h + (size_t)(n0 + node) * HID + seg * 16)
                                      : (magg + (size_t)(n0 + node) * HID + (seg - 8) * 16);
        float4 v0 = ((const float4*)srcp)[0];
        float4 v1 = ((const float4*)srcp)[1];
        float4 v2 = ((const float4*)srcp)[2];
        float4 v3 = ((const float4*)srcp)[3];
        uint4 q0; q0.x = cvtpk_bf16(v0.x, v0.y); q0.y = cvtpk_bf16(v0.z, v0.w);
                  q0.z = cvtpk_bf16(v1.x, v1.y); q0.w = cvtpk_bf16(v1.z, v1.w);
        uint4 q1; q1.x = cvtpk_bf16(v2.x, v2.y); q1.y = cvtpk_bf16(v2.z, v2.w);
                  q1.z = cvtpk_bf16(v3.x, v3.y); q1.w = cvtpk_bf16(v3.z, v3.w);
        *(uint4*)&hm[node * 264 + seg * 16] = q0;
        *(uint4*)&hm[node * 264 + seg * 16 + 8] = q1;
        if (seg < 8) {
            float* dst = &hf[node * 132 + seg * 16];
            ((float4*)dst)[0] = v0; ((float4*)dst)[1] = v1;
            ((float4*)dst)[2] = v2; ((float4*)dst)[3] = v3;
        }
    }
    __syncthreads();

    // ---- stage A: dh = silu([h|magg]@nw1 + nb1) ----
    bf16x8 bb[8];
#pragma unroll
    for (int kk = 0; kk < 8; ++kk)
        bb[kk] = *(const bf16x8*)&hm[lc * 264 + kk * 32 + lg * 8];
    f32x4 da[2] = {(f32x4){0.f,0.f,0.f,0.f}, (f32x4){0.f,0.f,0.f,0.f}};
#pragma unroll
    for (int t2 = 0; t2 < 2; ++t2) {
        int ct = wv * 2 + t2;
#pragma unroll
        for (int kk = 0; kk < 8; ++kk) {
            bf16x8 a = *(const bf16x8*)(nw1p + (size_t)((ct * 8 + kk) * 64 + lane) * 8);
            da[t2] = __builtin_amdgcn_mfma_f32_16x16x32_bf16(a, bb[kk], da[t2], 0, 0, 0);
        }
    }
#pragma unroll
    for (int t2 = 0; t2 < 2; ++t2) {
        int ct = wv * 2 + t2;
        const float4 bv = *(const float4*)(nb1 + ct * 16 + lg * 4);
        float m0 = fsilu(da[t2][0] + bv.x), m1 = fsilu(da[t2][1] + bv.y);
        float m2 = fsilu(da[t2][2] + bv.z), m3 = fsilu(da[t2][3] + bv.w);
        uint2 pk; pk.x = cvtpk_bf16(m0, m1); pk.y = cvtpk_bf16(m2, m3);
        *(uint2*)&dht[lc * SPAD + ct * 16 + lg * 4] = pk;
    }
    __syncthreads();

    // ---- stage B: h' = h + dh@nw2 + nb2 ----
    bf16x8 db[4];
#pragma unroll
    for (int kk = 0; kk < 4; ++kk)
        db[kk] = *(const bf16x8*)&dht[lc * SPAD + kk * 32 + lg * 8];
    f32x4 hb[2] = {(f32x4){0.f,0.f,0.f,0.f}, (f32x4){0.f,0.f,0.f,0.f}};
#pragma unroll
    for (int t2 = 0; t2 < 2; ++t2) {
        int ct = wv * 2 + t2;
#pragma unroll
        for (int kk = 0; kk < 4; ++kk) {
            bf16x8 a = *(const bf16x8*)(nw2p + (size_t)((ct * 4 + kk) * 64 + lane) * 8);
            hb[t2] = __builtin_amdgcn_mfma_f32_16x16x32_bf16(a, db[kk], hb[t2], 0, 0, 0);
        }
    }
#pragma unroll
    for (int t2 = 0; t2 < 2; ++t2) {
        int ct = wv * 2 + t2;
        const float4 bv = *(const float4*)(nb2 + ct * 16 + lg * 4);
        const float4 hv = *(const float4*)&hf[lc * 132 + ct * 16 + lg * 4];
        float o0 = hv.x + hb[t2][0] + bv.x, o1 = hv.y + hb[t2][1] + bv.y;
        float o2 = hv.z + hb[t2][2] + bv.z, o3 = hv.w + hb[t2][3] + bv.w;
        float4 o; o.x = o0; o.y = o1; o.z = o2; o.w = o3;
        *(float4*)(h + (size_t)(n0 + lc) * HID + ct * 16 + lg * 4) = o;
        uint2 pk; pk.x = cvtpk_bf16(o0, o1); pk.y = cvtpk_bf16(o2, o3);
        *(uint2*)&hpt[lc * SPAD + ct * 16 + lg * 4] = pk;
    }
    if (tid < 48) {
        int n = tid / 3, a = tid % 3;
        x[(size_t)(n0 + n) * 3 + a] += xdel[(size_t)(n0 + n) * 3 + a];
    }
    __syncthreads();

    // ---- stage C ----
    stageC(hpt, ewp, p1, p2, eob, n0, lane, wv, last);
}

// ---------------- per-graph mean pool + head MLP ----------------
__global__ void k_poolhead(const float* __restrict__ he,
                           const float* __restrict__ w1, const float* __restrict__ b1,
                           const float* __restrict__ w2, const float* __restrict__ b2,
                           float* __restrict__ out) {
    __shared__ float hp[HID], rs[HID];
    int gph = blockIdx.x, t = threadIdx.x;
    float s = 0.f;
    for (int j = 0; j < NN; ++j) s += he[(size_t)(gph * NN + j) * HID + t];
    hp[t] = s * (1.f / 128.f);
    __syncthreads();
    float acc = b1[t];
#pragma unroll 4
    for (int k = 0; k < HID; ++k) acc += hp[k] * w1[k * HID + t];
    rs[t] = fmaxf(acc, 0.f);
    __syncthreads();
    if (t < ONF) {
        float a = b2[t];
        for (int k = 0; k < HID; ++k) a += rs[k] * w2[k * ONF + t];
        out[gph * ONF + t] = a;
    }
}

extern "C" void kernel_launch(void* const* d_in, const int* in_sizes, int n_in,
                              void* d_out, int out_size, void* d_ws, size_t ws_size,
                              hipStream_t stream) {
    const float* h0        = (const float*)d_in[0];
    const float* x0        = (const float*)d_in[1];
    const float* emb_in_w  = (const float*)d_in[2];
    const float* emb_in_b  = (const float*)d_in[3];
    const float* edge_w1   = (const float*)d_in[4];
    const float* edge_b1   = (const float*)d_in[5];
    const float* edge_w2   = (const float*)d_in[6];
    const float* edge_b2   = (const float*)d_in[7];
    const float* att_w     = (const float*)d_in[8];
    const float* att_b     = (const float*)d_in[9];
    const float* node_w1   = (const float*)d_in[10];
    const float* node_b1   = (const float*)d_in[11];
    const float* node_w2   = (const float*)d_in[12];
    const float* node_b2   = (const float*)d_in[13];
    const float* coord_w1  = (const float*)d_in[14];
    const float* coord_b1  = (const float*)d_in[15];
    const float* coord_w2  = (const float*)d_in[16];
    const float* emb_out_w = (const float*)d_in[17];
    const float* emb_out_b = (const float*)d_in[18];
    const float* head_w1   = (const float*)d_in[19];
    const float* head_b1   = (const float*)d_in[20];
    const float* head_w2   = (const float*)d_in[21];
    const float* head_b2   = (const float*)d_in[22];

    float* ws    = (float*)d_ws;
    float* h_cur = ws;                   // BN*HID
    float* p1    = h_cur + BN * HID;     // BN*HID (h_emb at the end)
    float* p2    = p1 + BN * HID;        // BN*HID
    float* magg  = p2 + BN * HID;        // BN*HID
    float* xc    = magg + BN * HID;      // BN*3
    float* xdel  = xc + BN * 3;          // BN*3
    unsigned short* wpack = (unsigned short*)(xdel + BN * 3);  // U_TOT * 8 bf16

    k_packall<<<U_TOT / 256, 256, 0, stream>>>(edge_w2, coord_w1, node_w1, edge_w1,
                                               node_w2, emb_out_w, wpack);
    k_emb0<<<BN / 16, 256, 0, stream>>>(h0, x0, emb_in_w, emb_in_b,
                                        wpack + (size_t)U_EW * 8, h_cur, xc, p1, p2);
    for (int l = 0; l < NLAY; ++l) {
        const int last = (l == NLAY - 1);
        k_edge<<<BN, 256, 0, stream>>>(xc, p1, p2,
            edge_w1 + (size_t)l * 258 * HID, edge_b1 + l * HID,
            wpack + (size_t)(U_W2 + l * 2048) * 8, edge_b2 + l * HID,
            att_w + l * HID, att_b + l,
            wpack + (size_t)(U_C1 + l * 2048) * 8, coord_b1 + l * HID, coord_w2 + l * HID,
            magg, xdel);
        k_node2<<<BN / 16, 256, 0, stream>>>(h_cur, xc, magg, xdel,
            wpack + (size_t)(U_NW1 + l * 4096) * 8, node_b1 + l * HID,
            wpack + (size_t)(U_NW2 + l * 2048) * 8, node_b2 + l * HID,
            last ? wpack + (size_t)U_EOW * 8 : wpack + (size_t)(U_EW + (l + 1) * 4096) * 8,
            emb_out_b, p1, p2, last);
    }
    k_poolhead<<<NB, HID, 0, stream>>>(p1, head_w1, head_b1, head_w2, head_b2, (float*)d_out);
}

// Round 10
// 629.345 us; speedup vs baseline: 1.8902x; 1.4176x over previous
//
#include <hip/hip_runtime.h>
#include <math.h>

#define HID 128
#define NN 128      // nodes per graph
#define NB 16       // graphs
#define BN 2048     // total nodes
#define NLAY 4
#define INF 21
#define ONF 20
#define SPAD 136    // padded LDS row stride in bf16 elems (272B: 16B-aligned, 2-way b128 — free)

// pack regions in 16B units (8 bf16 elems each)
#define U_W2   0        // 4 x 2048   (K=128, N=128)
#define U_C1   8192     // 4 x 2048
#define U_NW1  16384    // 4 x 4096   (K=256, N=128)
#define U_EW   32768    // 4 x 4096   (virtual K=128, N=256 = [ew1a|ew1b])
#define U_NW2  49152    // 4 x 2048
#define U_EOW  57344    // 1 x 2048
#define U_TOT  59392

typedef __attribute__((ext_vector_type(8))) short bf16x8;
typedef __attribute__((ext_vector_type(4))) float f32x4;

__device__ __forceinline__ float frcp(float x) {
    float r; asm("v_rcp_f32 %0, %1" : "=v"(r) : "v"(x)); return r;
}
__device__ __forceinline__ float fsilu(float v) { return v * frcp(1.f + __expf(-v)); }
__device__ __forceinline__ float fsig(float v)  { return frcp(1.f + __expf(-v)); }
__device__ __forceinline__ unsigned cvtpk_bf16(float lo, float hi) {
    unsigned r; asm("v_cvt_pk_bf16_f32 %0, %1, %2" : "=v"(r) : "v"(lo), "v"(hi)); return r;
}
__device__ __forceinline__ unsigned short f2bf(float f) {
    union { float f; unsigned u; } v; v.f = f;
    unsigned r = v.u + 0x7fffu + ((v.u >> 16) & 1u);
    return (unsigned short)(r >> 16);
}
__device__ __forceinline__ float bf2f(unsigned short u) {
    union { unsigned u; float f; } v; v.u = ((unsigned)u) << 16;
    return v.f;
}

// ---------------- pack ALL weight matrices into bf16 A-fragments of W^T ----------------
// unit u (16B = 64-lane fragment slice /8): lane l holds W[k0+j][col], j=0..7.
__global__ void k_packall(const float* __restrict__ w2, const float* __restrict__ c1,
                          const float* __restrict__ nw1, const float* __restrict__ ew1,
                          const float* __restrict__ nw2, const float* __restrict__ eow,
                          unsigned short* __restrict__ out) {
    int u = blockIdx.x * 256 + threadIdx.x;
    int l = u & 63;
    const float* src; int k0, col;
    if (u < U_C1) {                       // edge_w2, K=128
        int f = u & 2047; src = w2 + (size_t)(u >> 11) * HID * HID;
        col = (f >> 8) * 16 + (l & 15); k0 = ((f >> 6) & 3) * 32 + (l >> 4) * 8;
    } else if (u < U_NW1) {               // coord_w1, K=128
        int f = u & 2047; src = c1 + (size_t)((u - U_C1) >> 11) * HID * HID;
        col = (f >> 8) * 16 + (l & 15); k0 = ((f >> 6) & 3) * 32 + (l >> 4) * 8;
    } else if (u < U_EW) {                // node_w1, K=256
        int f = u & 4095; src = nw1 + (size_t)((u - U_NW1) >> 12) * 256 * HID;
        col = (f >> 9) * 16 + (l & 15); k0 = ((f >> 6) & 7) * 32 + (l >> 4) * 8;
    } else if (u < U_NW2) {               // edge_w1[0:256] as virtual [128 x 256]
        int f = u & 4095; src = ew1 + (size_t)((u - U_EW) >> 12) * 258 * HID;
        int c = (f >> 8) * 16 + (l & 15);             // 0..255
        col = c & 127; k0 = ((f >> 6) & 3) * 32 + (l >> 4) * 8 + (c >= 128 ? 128 : 0);
    } else if (u < U_EOW) {               // node_w2, K=128
        int f = u & 2047; src = nw2 + (size_t)((u - U_NW2) >> 11) * HID * HID;
        col = (f >> 8) * 16 + (l & 15); k0 = ((f >> 6) & 3) * 32 + (l >> 4) * 8;
    } else {                              // emb_out_w, K=128
        int f = (u - U_EOW) & 2047; src = eow;
        col = (f >> 8) * 16 + (l & 15); k0 = ((f >> 6) & 3) * 32 + (l >> 4) * 8;
    }
    unsigned short tmp[8];
#pragma unroll
    for (int j = 0; j < 8; ++j) tmp[j] = f2bf(src[(size_t)(k0 + j) * HID + col]);
    *(bf16x8*)(out + (size_t)u * 8) = *(const bf16x8*)tmp;
}

// ---------------- shared stage-C: p = h'@[ew1a|ew1b] (or h_emb = h'@eow + eob) ----------------
__device__ __forceinline__ void stageC(const unsigned short* hpt, const unsigned short* ewp,
                                       float* __restrict__ p1, float* __restrict__ p2,
                                       const float* __restrict__ eob,
                                       int n0, int lane, int wv, int last) {
    const int lc = lane & 15, lg = lane >> 4;
    bf16x8 pb[4];
#pragma unroll
    for (int kk = 0; kk < 4; ++kk)
        pb[kk] = *(const bf16x8*)&hpt[lc * SPAD + kk * 32 + lg * 8];
    if (!last) {
#pragma unroll
        for (int t4 = 0; t4 < 4; ++t4) {
            int ct = wv * 4 + t4;
            f32x4 d = (f32x4){0.f, 0.f, 0.f, 0.f};
#pragma unroll
            for (int kk = 0; kk < 4; ++kk) {
                bf16x8 a = *(const bf16x8*)(ewp + (size_t)((ct * 4 + kk) * 64 + lane) * 8);
                d = __builtin_amdgcn_mfma_f32_16x16x32_bf16(a, pb[kk], d, 0, 0, 0);
            }
            int c = ct * 16 + lg * 4;
            float* dst = (c < 128) ? (p1 + (size_t)(n0 + lc) * HID + c)
                                   : (p2 + (size_t)(n0 + lc) * HID + (c - 128));
            float4 o; o.x = d[0]; o.y = d[1]; o.z = d[2]; o.w = d[3];
            *(float4*)dst = o;
        }
    } else {
#pragma unroll
        for (int t2 = 0; t2 < 2; ++t2) {
            int ct = wv * 2 + t2;
            f32x4 d = (f32x4){0.f, 0.f, 0.f, 0.f};
#pragma unroll
            for (int kk = 0; kk < 4; ++kk) {
                bf16x8 a = *(const bf16x8*)(ewp + (size_t)((ct * 4 + kk) * 64 + lane) * 8);
                d = __builtin_amdgcn_mfma_f32_16x16x32_bf16(a, pb[kk], d, 0, 0, 0);
            }
            int c = ct * 16 + lg * 4;
            const float4 bv = *(const float4*)(eob + c);
            float4 o; o.x = d[0] + bv.x; o.y = d[1] + bv.y; o.z = d[2] + bv.z; o.w = d[3] + bv.w;
            *(float4*)(p1 + (size_t)(n0 + lc) * HID + c) = o;
        }
    }
}

// ---------------- embed + layer-0 projections (16 nodes/block, MFMA proj) ----------------
__global__ __launch_bounds__(256) void k_emb0(
    const float* __restrict__ h0, const float* __restrict__ x0,
    const float* __restrict__ wemb, const float* __restrict__ bemb,
    const unsigned short* __restrict__ ewp0,
    float* __restrict__ h, float* __restrict__ x,
    float* __restrict__ p1, float* __restrict__ p2) {
    __shared__ float hraw[16 * INF];
    __shared__ unsigned short hpt[16 * SPAD];
    const int n0 = blockIdx.x * 16;
    const int tid = threadIdx.x, lane = tid & 63, wv = tid >> 6;
    for (int t = tid; t < 16 * INF; t += 256)          // 336 > 256: strided load
        hraw[t] = h0[(size_t)n0 * INF + t];
    if (tid < 48) x[(size_t)n0 * 3 + tid] = x0[(size_t)n0 * 3 + tid];
    __syncthreads();
#pragma unroll
    for (int ot = 0; ot < 4; ++ot) {
        int idx = tid + ot * 256;          // 1024 col-pairs
        int node = idx >> 6, cp = idx & 63;
        float a0 = bemb[cp * 2], a1 = bemb[cp * 2 + 1];
#pragma unroll
        for (int k = 0; k < INF; ++k) {
            float hv = hraw[node * INF + k];
            a0 = fmaf(hv, wemb[k * HID + cp * 2], a0);
            a1 = fmaf(hv, wemb[k * HID + cp * 2 + 1], a1);
        }
        float2 o; o.x = a0; o.y = a1;
        *(float2*)(h + (size_t)(n0 + node) * HID + cp * 2) = o;
        *(unsigned*)&hpt[node * SPAD + cp * 2] = cvtpk_bf16(a0, a1);
    }
    __syncthreads();
    stageC(hpt, ewp0, p1, p2, bemb /*unused*/, n0, lane, wv, 0);
}

// ---------------- edge pipeline: one block per node i, HALF-J split ----------------
// Two halves of 64 j-rows; each wave owns 16 rows per half. S = 64 rows -> 22.3 KB LDS.
// launch_bounds(256,4): unified VGPR+AGPR cap 128 — live state ~96 fits (r7 proved 128 fits).
// (256,6)/(256,7) forced spills (rounds 8/9: FETCH 268-288 MB scratch traffic).
__global__ __launch_bounds__(256, 4) void k_edge(
    const float* __restrict__ x, const float* __restrict__ p1g, const float* __restrict__ p2g,
    const float* __restrict__ ew1, const float* __restrict__ eb1,
    const unsigned short* __restrict__ w2p, const float* __restrict__ b2,
    const float* __restrict__ attw, const float* __restrict__ attbp,
    const unsigned short* __restrict__ c1p, const float* __restrict__ c1b, const float* __restrict__ c2,
    float* __restrict__ magg, float* __restrict__ xdel) {
    __shared__ unsigned short S[64 * SPAD];    // silu(pre) then m (ungated); rows wave-private
    __shared__ float cds[NN * 3];
    __shared__ float rad[NN];
    __shared__ float phis[NN];
    __shared__ float gatev[64];                // per-half gates, wave-private slices
    __shared__ float red[4 * HID];

    const int i = blockIdx.x;
    const int base = i & ~127;
    const int irel = i & 127;
    const int tid = threadIdx.x;
    const int lane = tid & 63;
    const int wv = tid >> 6;
    const int lc = lane & 15, lg = lane >> 4;
    const int r0 = wv * 16;                    // wave's local row base in S

    // ---- phase 0: coord diffs + radial (block-wide) ----
    const float xi0 = x[i * 3 + 0], xi1 = x[i * 3 + 1], xi2 = x[i * 3 + 2];
    if (tid < NN) {
        int j = base + tid;
        float d0 = xi0 - x[j * 3 + 0], d1 = xi1 - x[j * 3 + 1], d2 = xi2 - x[j * 3 + 2];
        cds[tid * 3 + 0] = d0; cds[tid * 3 + 1] = d1; cds[tid * 3 + 2] = d2;
        rad[tid] = d0 * d0 + d1 * d1 + d2 * d2;
    }
    __syncthreads();

    // hoisted S-build constants
    const int bl = lane & 31, bh = lane >> 5;
    const int col0 = bl * 4;
    const float4 wrv = *(const float4*)(ew1 + 256 * HID + col0);
    float4 bcv = *(const float4*)(ew1 + 257 * HID + col0);
    {
        const float4 p1v = *(const float4*)(p1g + (size_t)i * HID + col0);
        const float4 ebv = *(const float4*)(eb1 + col0);
        bcv.x += ebv.x + p1v.x; bcv.y += ebv.y + p1v.y;
        bcv.z += ebv.z + p1v.z; bcv.w += ebv.w + p1v.w;
    }
    const float attb = attbp[0];

    const int p = tid & 63;          // feature pair for m_agg
    float magg0 = 0.f, magg1 = 0.f;  // accumulated across halves

    for (int half = 0; half < 2; ++half) {
        const int jb = half * 64;

        // ---- S = silu(pre), wave-private rows [r0, r0+16) of this half ----
#pragma unroll
        for (int it = 0; it < 8; ++it) {
            int lrow = r0 + it * 2 + bh;
            int grow = jb + lrow;
            float rv = rad[grow];
            const float4 p2v = *(const float4*)(p2g + (size_t)(base + grow) * HID + col0);
            float v0 = fsilu(fmaf(rv, wrv.x, p2v.x + bcv.x));
            float v1 = fsilu(fmaf(rv, wrv.y, p2v.y + bcv.y));
            float v2 = fsilu(fmaf(rv, wrv.z, p2v.z + bcv.z));
            float v3 = fsilu(fmaf(rv, wrv.w, p2v.w + bcv.w));
            uint2 pk; pk.x = cvtpk_bf16(v0, v1); pk.y = cvtpk_bf16(v2, v3);
            *(uint2*)(S + lrow * SPAD + col0) = pk;
        }

        // ---- GEMM1: P = W2^T @ S^T (wave's 16 columns) ----
        bf16x8 bf[4];
#pragma unroll
        for (int kk = 0; kk < 4; ++kk)
            bf[kk] = *(const bf16x8*)&S[(r0 + lc) * SPAD + kk * 32 + lg * 8];
        f32x4 acc[8];
#pragma unroll
        for (int ct = 0; ct < 8; ++ct) acc[ct] = (f32x4){0.f, 0.f, 0.f, 0.f};
        __builtin_amdgcn_s_setprio(1);
#pragma unroll
        for (int ct = 0; ct < 8; ++ct)
#pragma unroll
            for (int kk = 0; kk < 4; ++kk) {
                bf16x8 a = *(const bf16x8*)(w2p + (size_t)((ct * 4 + kk) * 64 + lane) * 8);
                acc[ct] = __builtin_amdgcn_mfma_f32_16x16x32_bf16(a, bf[kk], acc[ct], 0, 0, 0);
            }
        __builtin_amdgcn_s_setprio(0);

        // ---- epilogue 1: m = silu(P + b2[c]) -> S (ungated); att partial ----
        float patt = 0.f;
#pragma unroll
        for (int ct = 0; ct < 8; ++ct) {
            const float4 b2v = *(const float4*)(b2 + ct * 16 + lg * 4);
            const float4 awv = *(const float4*)(attw + ct * 16 + lg * 4);
            f32x4 a = acc[ct];
            float m0 = fsilu(a[0] + b2v.x), m1 = fsilu(a[1] + b2v.y);
            float m2 = fsilu(a[2] + b2v.z), m3 = fsilu(a[3] + b2v.w);
            patt += m0 * awv.x + m1 * awv.y + m2 * awv.z + m3 * awv.w;
            uint2 pk; pk.x = cvtpk_bf16(m0, m1); pk.y = cvtpk_bf16(m2, m3);
            *(uint2*)(S + (r0 + lc) * SPAD + ct * 16 + lg * 4) = pk;
        }
        patt += __shfl_xor(patt, 16, 64); patt += __shfl_xor(patt, 32, 64);
        const float gv = (jb + r0 + lc == irel) ? 0.f : fsig(patt + attb);
        if (lg == 0) gatev[r0 + lc] = gv;

        // ---- GEMM2: E2 = C1^T @ m^T ----
        bf16x8 bg[4];
#pragma unroll
        for (int kk = 0; kk < 4; ++kk)
            bg[kk] = *(const bf16x8*)&S[(r0 + lc) * SPAD + kk * 32 + lg * 8];
        f32x4 acc2[8];
#pragma unroll
        for (int ct = 0; ct < 8; ++ct) acc2[ct] = (f32x4){0.f, 0.f, 0.f, 0.f};
        __builtin_amdgcn_s_setprio(1);
#pragma unroll
        for (int ct = 0; ct < 8; ++ct)
#pragma unroll
            for (int kk = 0; kk < 4; ++kk) {
                bf16x8 a = *(const bf16x8*)(c1p + (size_t)((ct * 4 + kk) * 64 + lane) * 8);
                acc2[ct] = __builtin_amdgcn_mfma_f32_16x16x32_bf16(a, bg[kk], acc2[ct], 0, 0, 0);
            }
        __builtin_amdgcn_s_setprio(0);

        // ---- phi[j] = sum_c silu(g_j*E2 + c1b)*c2 ----
        float pp = 0.f;
#pragma unroll
        for (int ct = 0; ct < 8; ++ct) {
            const float4 cbv = *(const float4*)(c1b + ct * 16 + lg * 4);
            const float4 cwv = *(const float4*)(c2 + ct * 16 + lg * 4);
            f32x4 a = acc2[ct];
            pp += fsilu(fmaf(gv, a[0], cbv.x)) * cwv.x + fsilu(fmaf(gv, a[1], cbv.y)) * cwv.y +
                  fsilu(fmaf(gv, a[2], cbv.z)) * cwv.z + fsilu(fmaf(gv, a[3], cbv.w)) * cwv.w;
        }
        pp += __shfl_xor(pp, 16, 64); pp += __shfl_xor(pp, 32, 64);
        if (lg == 0) phis[jb + r0 + lc] = pp;

        // ---- m_agg partial: wave's 16 rows of this half ----
#pragma unroll
        for (int q = 0; q < 16; ++q) {
            float g = gatev[r0 + q];
            unsigned u = *(const unsigned*)(S + (r0 + q) * SPAD + p * 2);
            magg0 = fmaf(g, bf2f((unsigned short)(u & 0xffffu)), magg0);
            magg1 = fmaf(g, bf2f((unsigned short)(u >> 16)), magg1);
        }
    }

    {
        float2 pr; pr.x = magg0; pr.y = magg1;
        *(float2*)(red + wv * HID + p * 2) = pr;
    }
    __syncthreads();   // B1: phis + red complete

    if (tid < NN) {
        float ph = phis[tid];
        cds[tid * 3 + 0] *= ph; cds[tid * 3 + 1] *= ph; cds[tid * 3 + 2] *= ph;
    }
    if (tid < HID)
        magg[(size_t)i * HID + tid] = red[tid] + red[HID + tid] + red[2 * HID + tid] + red[3 * HID + tid];
    __syncthreads();   // B2: cds scaled

    if (tid < 192) {
        const int a = tid >> 6, ln = tid & 63;
        float v = cds[ln * 3 + a] + cds[(ln + 64) * 3 + a];
#pragma unroll
        for (int off = 1; off <= 32; off <<= 1) v += __shfl_xor(v, off, 64);
        if (ln == 0) xdel[i * 3 + a] = v * (1.f / 127.f);
    }
}

// ---------------- node path via MFMA: 16 nodes/block, 128 blocks ----------------
__global__ __launch_bounds__(256) void k_node2(
    float* __restrict__ h, float* __restrict__ x,
    const float* __restrict__ magg, const float* __restrict__ xdel,
    const unsigned short* __restrict__ nw1p, const float* __restrict__ nb1,
    const unsigned short* __restrict__ nw2p, const float* __restrict__ nb2,
    const unsigned short* __restrict__ ewp, const float* __restrict__ eob,
    float* __restrict__ p1, float* __restrict__ p2, int last) {
    __shared__ unsigned short hm[16 * 264];   // [node][h(128)|magg(128)] bf16
    __shared__ float hf[16 * 132];            // h fp32 tile (padded)
    __shared__ unsigned short dht[16 * SPAD];
    __shared__ unsigned short hpt[16 * SPAD];

    const int n0 = blockIdx.x * 16;
    const int tid = threadIdx.x, lane = tid & 63, wv = tid >> 6;
    const int lc = lane & 15, lg = lane >> 4;

    {
        int node = tid >> 4, seg = tid & 15;
        const float* srcp = (seg < 8) ? (h + (size_t)(n0 + node) * HID + seg * 16)
                                      : (magg + (size_t)(n0 + node) * HID + (seg - 8) * 16);
        float4 v0 = ((const float4*)srcp)[0];
        float4 v1 = ((const float4*)srcp)[1];
        float4 v2 = ((const float4*)srcp)[2];
        float4 v3 = ((const float4*)srcp)[3];
        uint4 q0; q0.x = cvtpk_bf16(v0.x, v0.y); q0.y = cvtpk_bf16(v0.z, v0.w);
                  q0.z = cvtpk_bf16(v1.x, v1.y); q0.w = cvtpk_bf16(v1.z, v1.w);
        uint4 q1; q1.x = cvtpk_bf16(v2.x, v2.y); q1.y = cvtpk_bf16(v2.z, v2.w);
                  q1.z = cvtpk_bf16(v3.x, v3.y); q1.w = cvtpk_bf16(v3.z, v3.w);
        *(uint4*)&hm[node * 264 + seg * 16] = q0;
        *(uint4*)&hm[node * 264 + seg * 16 + 8] = q1;
        if (seg < 8) {
            float* dst = &hf[node * 132 + seg * 16];
            ((float4*)dst)[0] = v0; ((float4*)dst)[1] = v1;
            ((float4*)dst)[2] = v2; ((float4*)dst)[3] = v3;
        }
    }
    __syncthreads();

    // ---- stage A: dh = silu([h|magg]@nw1 + nb1) ----
    bf16x8 bb[8];
#pragma unroll
    for (int kk = 0; kk < 8; ++kk)
        bb[kk] = *(const bf16x8*)&hm[lc * 264 + kk * 32 + lg * 8];
    f32x4 da[2] = {(f32x4){0.f,0.f,0.f,0.f}, (f32x4){0.f,0.f,0.f,0.f}};
#pragma unroll
    for (int t2 = 0; t2 < 2; ++t2) {
        int ct = wv * 2 + t2;
#pragma unroll
        for (int kk = 0; kk < 8; ++kk) {
            bf16x8 a = *(const bf16x8*)(nw1p + (size_t)((ct * 8 + kk) * 64 + lane) * 8);
            da[t2] = __builtin_amdgcn_mfma_f32_16x16x32_bf16(a, bb[kk], da[t2], 0, 0, 0);
        }
    }
#pragma unroll
    for (int t2 = 0; t2 < 2; ++t2) {
        int ct = wv * 2 + t2;
        const float4 bv = *(const float4*)(nb1 + ct * 16 + lg * 4);
        float m0 = fsilu(da[t2][0] + bv.x), m1 = fsilu(da[t2][1] + bv.y);
        float m2 = fsilu(da[t2][2] + bv.z), m3 = fsilu(da[t2][3] + bv.w);
        uint2 pk; pk.x = cvtpk_bf16(m0, m1); pk.y = cvtpk_bf16(m2, m3);
        *(uint2*)&dht[lc * SPAD + ct * 16 + lg * 4] = pk;
    }
    __syncthreads();

    // ---- stage B: h' = h + dh@nw2 + nb2 ----
    bf16x8 db[4];
#pragma unroll
    for (int kk = 0; kk < 4; ++kk)
        db[kk] = *(const bf16x8*)&dht[lc * SPAD + kk * 32 + lg * 8];
    f32x4 hb[2] = {(f32x4){0.f,0.f,0.f,0.f}, (f32x4){0.f,0.f,0.f,0.f}};
#pragma unroll
    for (int t2 = 0; t2 < 2; ++t2) {
        int ct = wv * 2 + t2;
#pragma unroll
        for (int kk = 0; kk < 4; ++kk) {
            bf16x8 a = *(const bf16x8*)(nw2p + (size_t)((ct * 4 + kk) * 64 + lane) * 8);
            hb[t2] = __builtin_amdgcn_mfma_f32_16x16x32_bf16(a, db[kk], hb[t2], 0, 0, 0);
        }
    }
#pragma unroll
    for (int t2 = 0; t2 < 2; ++t2) {
        int ct = wv * 2 + t2;
        const float4 bv = *(const float4*)(nb2 + ct * 16 + lg * 4);
        const float4 hv = *(const float4*)&hf[lc * 132 + ct * 16 + lg * 4];
        float o0 = hv.x + hb[t2][0] + bv.x, o1 = hv.y + hb[t2][1] + bv.y;
        float o2 = hv.z + hb[t2][2] + bv.z, o3 = hv.w + hb[t2][3] + bv.w;
        float4 o; o.x = o0; o.y = o1; o.z = o2; o.w = o3;
        *(float4*)(h + (size_t)(n0 + lc) * HID + ct * 16 + lg * 4) = o;
        uint2 pk; pk.x = cvtpk_bf16(o0, o1); pk.y = cvtpk_bf16(o2, o3);
        *(uint2*)&hpt[lc * SPAD + ct * 16 + lg * 4] = pk;
    }
    if (tid < 48) {
        int n = tid / 3, a = tid % 3;
        x[(size_t)(n0 + n) * 3 + a] += xdel[(size_t)(n0 + n) * 3 + a];
    }
    __syncthreads();

    // ---- stage C ----
    stageC(hpt, ewp, p1, p2, eob, n0, lane, wv, last);
}

// ---------------- per-graph mean pool + head MLP ----------------
__global__ void k_poolhead(const float* __restrict__ he,
                           const float* __restrict__ w1, const float* __restrict__ b1,
                           const float* __restrict__ w2, const float* __restrict__ b2,
                           float* __restrict__ out) {
    __shared__ float hp[HID], rs[HID];
    int gph = blockIdx.x, t = threadIdx.x;
    float s = 0.f;
    for (int j = 0; j < NN; ++j) s += he[(size_t)(gph * NN + j) * HID + t];
    hp[t] = s * (1.f / 128.f);
    __syncthreads();
    float acc = b1[t];
#pragma unroll 4
    for (int k = 0; k < HID; ++k) acc += hp[k] * w1[k * HID + t];
    rs[t] = fmaxf(acc, 0.f);
    __syncthreads();
    if (t < ONF) {
        float a = b2[t];
        for (int k = 0; k < HID; ++k) a += rs[k] * w2[k * ONF + t];
        out[gph * ONF + t] = a;
    }
}

extern "C" void kernel_launch(void* const* d_in, const int* in_sizes, int n_in,
                              void* d_out, int out_size, void* d_ws, size_t ws_size,
                              hipStream_t stream) {
    const float* h0        = (const float*)d_in[0];
    const float* x0        = (const float*)d_in[1];
    const float* emb_in_w  = (const float*)d_in[2];
    const float* emb_in_b  = (const float*)d_in[3];
    const float* edge_w1   = (const float*)d_in[4];
    const float* edge_b1   = (const float*)d_in[5];
    const float* edge_w2   = (const float*)d_in[6];
    const float* edge_b2   = (const float*)d_in[7];
    const float* att_w     = (const float*)d_in[8];
    const float* att_b     = (const float*)d_in[9];
    const float* node_w1   = (const float*)d_in[10];
    const float* node_b1   = (const float*)d_in[11];
    const float* node_w2   = (const float*)d_in[12];
    const float* node_b2   = (const float*)d_in[13];
    const float* coord_w1  = (const float*)d_in[14];
    const float* coord_b1  = (const float*)d_in[15];
    const float* coord_w2  = (const float*)d_in[16];
    const float* emb_out_w = (const float*)d_in[17];
    const float* emb_out_b = (const float*)d_in[18];
    const float* head_w1   = (const float*)d_in[19];
    const float* head_b1   = (const float*)d_in[20];
    const float* head_w2   = (const float*)d_in[21];
    const float* head_b2   = (const float*)d_in[22];

    float* ws    = (float*)d_ws;
    float* h_cur = ws;                   // BN*HID
    float* p1    = h_cur + BN * HID;     // BN*HID (h_emb at the end)
    float* p2    = p1 + BN * HID;        // BN*HID
    float* magg  = p2 + BN * HID;        // BN*HID
    float* xc    = magg + BN * HID;      // BN*3
    float* xdel  = xc + BN * 3;          // BN*3
    unsigned short* wpack = (unsigned short*)(xdel + BN * 3);  // U_TOT * 8 bf16

    k_packall<<<U_TOT / 256, 256, 0, stream>>>(edge_w2, coord_w1, node_w1, edge_w1,
                                               node_w2, emb_out_w, wpack);
    k_emb0<<<BN / 16, 256, 0, stream>>>(h0, x0, emb_in_w, emb_in_b,
                                        wpack + (size_t)U_EW * 8, h_cur, xc, p1, p2);
    for (int l = 0; l < NLAY; ++l) {
        const int last = (l == NLAY - 1);
        k_edge<<<BN, 256, 0, stream>>>(xc, p1, p2,
            edge_w1 + (size_t)l * 258 * HID, edge_b1 + l * HID,
            wpack + (size_t)(U_W2 + l * 2048) * 8, edge_b2 + l * HID,
            att_w + l * HID, att_b + l,
            wpack + (size_t)(U_C1 + l * 2048) * 8, coord_b1 + l * HID, coord_w2 + l * HID,
            magg, xdel);
        k_node2<<<BN / 16, 256, 0, stream>>>(h_cur, xc, magg, xdel,
            wpack + (size_t)(U_NW1 + l * 4096) * 8, node_b1 + l * HID,
            wpack + (size_t)(U_NW2 + l * 2048) * 8, node_b2 + l * HID,
            last ? wpack + (size_t)U_EOW * 8 : wpack + (size_t)(U_EW + (l + 1) * 4096) * 8,
            emb_out_b, p1, p2, last);
    }
    k_poolhead<<<NB, HID, 0, stream>>>(p1, head_w1, head_b1, head_w2, head_b2, (float*)d_out);
}

// Round 11
// 629.136 us; speedup vs baseline: 1.8908x; 1.0003x over previous
//
#include <hip/hip_runtime.h>
#include <math.h>

#define HID 128
#define NN 128      // nodes per graph
#define NB 16       // graphs
#define BN 2048     // total nodes
#define NLAY 4
#define INF 21
#define ONF 20
#define SPAD 136    // padded LDS row stride in bf16 elems (272B: 16B-aligned, 2-way b128 — free)

// pack regions in 16B units (8 bf16 elems each)
#define U_W2   0        // 4 x 2048   (K=128, N=128)
#define U_C1   8192     // 4 x 2048
#define U_NW1  16384    // 4 x 4096   (K=256, N=128)
#define U_EW   32768    // 4 x 4096   (virtual K=128, N=256 = [ew1a|ew1b])
#define U_NW2  49152    // 4 x 2048
#define U_EOW  57344    // 1 x 2048
#define U_TOT  59392

typedef __attribute__((ext_vector_type(8))) short bf16x8;
typedef __attribute__((ext_vector_type(4))) float f32x4;

__device__ __forceinline__ float frcp(float x) {
    float r; asm("v_rcp_f32 %0, %1" : "=v"(r) : "v"(x)); return r;
}
__device__ __forceinline__ float fsilu(float v) { return v * frcp(1.f + __expf(-v)); }
__device__ __forceinline__ float fsig(float v)  { return frcp(1.f + __expf(-v)); }
__device__ __forceinline__ unsigned cvtpk_bf16(float lo, float hi) {
    unsigned r; asm("v_cvt_pk_bf16_f32 %0, %1, %2" : "=v"(r) : "v"(lo), "v"(hi)); return r;
}
__device__ __forceinline__ unsigned short f2bf(float f) {
    union { float f; unsigned u; } v; v.f = f;
    unsigned r = v.u + 0x7fffu + ((v.u >> 16) & 1u);
    return (unsigned short)(r >> 16);
}
__device__ __forceinline__ float bf2f(unsigned short u) {
    union { unsigned u; float f; } v; v.u = ((unsigned)u) << 16;
    return v.f;
}

// ---------------- pack ALL weight matrices into bf16 A-fragments of W^T ----------------
// unit u (16B = 64-lane fragment slice /8): lane l holds W[k0+j][col], j=0..7.
__global__ void k_packall(const float* __restrict__ w2, const float* __restrict__ c1,
                          const float* __restrict__ nw1, const float* __restrict__ ew1,
                          const float* __restrict__ nw2, const float* __restrict__ eow,
                          unsigned short* __restrict__ out) {
    int u = blockIdx.x * 256 + threadIdx.x;
    int l = u & 63;
    const float* src; int k0, col;
    if (u < U_C1) {                       // edge_w2, K=128
        int f = u & 2047; src = w2 + (size_t)(u >> 11) * HID * HID;
        col = (f >> 8) * 16 + (l & 15); k0 = ((f >> 6) & 3) * 32 + (l >> 4) * 8;
    } else if (u < U_NW1) {               // coord_w1, K=128
        int f = u & 2047; src = c1 + (size_t)((u - U_C1) >> 11) * HID * HID;
        col = (f >> 8) * 16 + (l & 15); k0 = ((f >> 6) & 3) * 32 + (l >> 4) * 8;
    } else if (u < U_EW) {                // node_w1, K=256
        int f = u & 4095; src = nw1 + (size_t)((u - U_NW1) >> 12) * 256 * HID;
        col = (f >> 9) * 16 + (l & 15); k0 = ((f >> 6) & 7) * 32 + (l >> 4) * 8;
    } else if (u < U_NW2) {               // edge_w1[0:256] as virtual [128 x 256]
        int f = u & 4095; src = ew1 + (size_t)((u - U_EW) >> 12) * 258 * HID;
        int c = (f >> 8) * 16 + (l & 15);             // 0..255
        col = c & 127; k0 = ((f >> 6) & 3) * 32 + (l >> 4) * 8 + (c >= 128 ? 128 : 0);
    } else if (u < U_EOW) {               // node_w2, K=128
        int f = u & 2047; src = nw2 + (size_t)((u - U_NW2) >> 11) * HID * HID;
        col = (f >> 8) * 16 + (l & 15); k0 = ((f >> 6) & 3) * 32 + (l >> 4) * 8;
    } else {                              // emb_out_w, K=128
        int f = (u - U_EOW) & 2047; src = eow;
        col = (f >> 8) * 16 + (l & 15); k0 = ((f >> 6) & 3) * 32 + (l >> 4) * 8;
    }
    unsigned short tmp[8];
#pragma unroll
    for (int j = 0; j < 8; ++j) tmp[j] = f2bf(src[(size_t)(k0 + j) * HID + col]);
    *(bf16x8*)(out + (size_t)u * 8) = *(const bf16x8*)tmp;
}

// ---------------- shared stage-C: p = h'@[ew1a|ew1b] (or h_emb = h'@eow + eob) ----------------
__device__ __forceinline__ void stageC(const unsigned short* hpt, const unsigned short* ewp,
                                       float* __restrict__ p1, float* __restrict__ p2,
                                       const float* __restrict__ eob,
                                       int n0, int lane, int wv, int last) {
    const int lc = lane & 15, lg = lane >> 4;
    bf16x8 pb[4];
#pragma unroll
    for (int kk = 0; kk < 4; ++kk)
        pb[kk] = *(const bf16x8*)&hpt[lc * SPAD + kk * 32 + lg * 8];
    if (!last) {
#pragma unroll
        for (int t4 = 0; t4 < 4; ++t4) {
            int ct = wv * 4 + t4;
            f32x4 d = (f32x4){0.f, 0.f, 0.f, 0.f};
#pragma unroll
            for (int kk = 0; kk < 4; ++kk) {
                bf16x8 a = *(const bf16x8*)(ewp + (size_t)((ct * 4 + kk) * 64 + lane) * 8);
                d = __builtin_amdgcn_mfma_f32_16x16x32_bf16(a, pb[kk], d, 0, 0, 0);
            }
            int c = ct * 16 + lg * 4;
            float* dst = (c < 128) ? (p1 + (size_t)(n0 + lc) * HID + c)
                                   : (p2 + (size_t)(n0 + lc) * HID + (c - 128));
            float4 o; o.x = d[0]; o.y = d[1]; o.z = d[2]; o.w = d[3];
            *(float4*)dst = o;
        }
    } else {
#pragma unroll
        for (int t2 = 0; t2 < 2; ++t2) {
            int ct = wv * 2 + t2;
            f32x4 d = (f32x4){0.f, 0.f, 0.f, 0.f};
#pragma unroll
            for (int kk = 0; kk < 4; ++kk) {
                bf16x8 a = *(const bf16x8*)(ewp + (size_t)((ct * 4 + kk) * 64 + lane) * 8);
                d = __builtin_amdgcn_mfma_f32_16x16x32_bf16(a, pb[kk], d, 0, 0, 0);
            }
            int c = ct * 16 + lg * 4;
            const float4 bv = *(const float4*)(eob + c);
            float4 o; o.x = d[0] + bv.x; o.y = d[1] + bv.y; o.z = d[2] + bv.z; o.w = d[3] + bv.w;
            *(float4*)(p1 + (size_t)(n0 + lc) * HID + c) = o;
        }
    }
}

// ---------------- embed + layer-0 projections (16 nodes/block, MFMA proj) ----------------
__global__ __launch_bounds__(256) void k_emb0(
    const float* __restrict__ h0, const float* __restrict__ x0,
    const float* __restrict__ wemb, const float* __restrict__ bemb,
    const unsigned short* __restrict__ ewp0,
    float* __restrict__ h, float* __restrict__ x,
    float* __restrict__ p1, float* __restrict__ p2) {
    __shared__ float hraw[16 * INF];
    __shared__ unsigned short hpt[16 * SPAD];
    const int n0 = blockIdx.x * 16;
    const int tid = threadIdx.x, lane = tid & 63, wv = tid >> 6;
    for (int t = tid; t < 16 * INF; t += 256)          // 336 > 256: strided load
        hraw[t] = h0[(size_t)n0 * INF + t];
    if (tid < 48) x[(size_t)n0 * 3 + tid] = x0[(size_t)n0 * 3 + tid];
    __syncthreads();
#pragma unroll
    for (int ot = 0; ot < 4; ++ot) {
        int idx = tid + ot * 256;          // 1024 col-pairs
        int node = idx >> 6, cp = idx & 63;
        float a0 = bemb[cp * 2], a1 = bemb[cp * 2 + 1];
#pragma unroll
        for (int k = 0; k < INF; ++k) {
            float hv = hraw[node * INF + k];
            a0 = fmaf(hv, wemb[k * HID + cp * 2], a0);
            a1 = fmaf(hv, wemb[k * HID + cp * 2 + 1], a1);
        }
        float2 o; o.x = a0; o.y = a1;
        *(float2*)(h + (size_t)(n0 + node) * HID + cp * 2) = o;
        *(unsigned*)&hpt[node * SPAD + cp * 2] = cvtpk_bf16(a0, a1);
    }
    __syncthreads();
    stageC(hpt, ewp0, p1, p2, bemb /*unused*/, n0, lane, wv, 0);
}

// ---------------- edge pipeline: one block per node i, HALF-J split ----------------
// Two halves of 64 j-rows; each wave owns 16 rows per half. S = 64 rows -> 22.3 KB LDS.
// #pragma unroll 1 on the half loop is ESSENTIAL: an unrolled 2-trip body lets the
// scheduler interleave both halves' GEMM chains (~200 live regs -> spill; rounds 8-10:
// FETCH 168-288 MB of scratch traffic). Sequential halves need ~84 regs.
__global__ __launch_bounds__(256, 4) void k_edge(
    const float* __restrict__ x, const float* __restrict__ p1g, const float* __restrict__ p2g,
    const float* __restrict__ ew1, const float* __restrict__ eb1,
    const unsigned short* __restrict__ w2p, const float* __restrict__ b2,
    const float* __restrict__ attw, const float* __restrict__ attbp,
    const unsigned short* __restrict__ c1p, const float* __restrict__ c1b, const float* __restrict__ c2,
    float* __restrict__ magg, float* __restrict__ xdel) {
    __shared__ unsigned short S[64 * SPAD];    // silu(pre) then m (ungated); rows wave-private
    __shared__ float cds[NN * 3];
    __shared__ float rad[NN];
    __shared__ float phis[NN];
    __shared__ float gatev[64];                // per-half gates, wave-private slices
    __shared__ float red[4 * HID];

    const int i = blockIdx.x;
    const int base = i & ~127;
    const int irel = i & 127;
    const int tid = threadIdx.x;
    const int lane = tid & 63;
    const int wv = tid >> 6;
    const int lc = lane & 15, lg = lane >> 4;
    const int r0 = wv * 16;                    // wave's local row base in S

    // ---- phase 0: coord diffs + radial (block-wide) ----
    const float xi0 = x[i * 3 + 0], xi1 = x[i * 3 + 1], xi2 = x[i * 3 + 2];
    if (tid < NN) {
        int j = base + tid;
        float d0 = xi0 - x[j * 3 + 0], d1 = xi1 - x[j * 3 + 1], d2 = xi2 - x[j * 3 + 2];
        cds[tid * 3 + 0] = d0; cds[tid * 3 + 1] = d1; cds[tid * 3 + 2] = d2;
        rad[tid] = d0 * d0 + d1 * d1 + d2 * d2;
    }
    __syncthreads();

    // hoisted S-build constants
    const int bl = lane & 31, bh = lane >> 5;
    const int col0 = bl * 4;
    const float4 wrv = *(const float4*)(ew1 + 256 * HID + col0);
    float4 bcv = *(const float4*)(ew1 + 257 * HID + col0);
    {
        const float4 p1v = *(const float4*)(p1g + (size_t)i * HID + col0);
        const float4 ebv = *(const float4*)(eb1 + col0);
        bcv.x += ebv.x + p1v.x; bcv.y += ebv.y + p1v.y;
        bcv.z += ebv.z + p1v.z; bcv.w += ebv.w + p1v.w;
    }
    const float attb = attbp[0];

    const int p = tid & 63;          // feature pair for m_agg
    float magg0 = 0.f, magg1 = 0.f;  // accumulated across halves

#pragma unroll 1
    for (int half = 0; half < 2; ++half) {
        const int jb = half * 64;

        // ---- S = silu(pre), wave-private rows [r0, r0+16) of this half ----
#pragma unroll
        for (int it = 0; it < 8; ++it) {
            int lrow = r0 + it * 2 + bh;
            int grow = jb + lrow;
            float rv = rad[grow];
            const float4 p2v = *(const float4*)(p2g + (size_t)(base + grow) * HID + col0);
            float v0 = fsilu(fmaf(rv, wrv.x, p2v.x + bcv.x));
            float v1 = fsilu(fmaf(rv, wrv.y, p2v.y + bcv.y));
            float v2 = fsilu(fmaf(rv, wrv.z, p2v.z + bcv.z));
            float v3 = fsilu(fmaf(rv, wrv.w, p2v.w + bcv.w));
            uint2 pk; pk.x = cvtpk_bf16(v0, v1); pk.y = cvtpk_bf16(v2, v3);
            *(uint2*)(S + lrow * SPAD + col0) = pk;
        }

        // ---- GEMM1: P = W2^T @ S^T (wave's 16 columns) ----
        bf16x8 bf[4];
#pragma unroll
        for (int kk = 0; kk < 4; ++kk)
            bf[kk] = *(const bf16x8*)&S[(r0 + lc) * SPAD + kk * 32 + lg * 8];
        f32x4 acc[8];
#pragma unroll
        for (int ct = 0; ct < 8; ++ct) acc[ct] = (f32x4){0.f, 0.f, 0.f, 0.f};
        __builtin_amdgcn_s_setprio(1);
#pragma unroll
        for (int ct = 0; ct < 8; ++ct)
#pragma unroll
            for (int kk = 0; kk < 4; ++kk) {
                bf16x8 a = *(const bf16x8*)(w2p + (size_t)((ct * 4 + kk) * 64 + lane) * 8);
                acc[ct] = __builtin_amdgcn_mfma_f32_16x16x32_bf16(a, bf[kk], acc[ct], 0, 0, 0);
            }
        __builtin_amdgcn_s_setprio(0);

        // ---- epilogue 1: m = silu(P + b2[c]) -> S (ungated); att partial ----
        float patt = 0.f;
#pragma unroll
        for (int ct = 0; ct < 8; ++ct) {
            const float4 b2v = *(const float4*)(b2 + ct * 16 + lg * 4);
            const float4 awv = *(const float4*)(attw + ct * 16 + lg * 4);
            f32x4 a = acc[ct];
            float m0 = fsilu(a[0] + b2v.x), m1 = fsilu(a[1] + b2v.y);
            float m2 = fsilu(a[2] + b2v.z), m3 = fsilu(a[3] + b2v.w);
            patt += m0 * awv.x + m1 * awv.y + m2 * awv.z + m3 * awv.w;
            uint2 pk; pk.x = cvtpk_bf16(m0, m1); pk.y = cvtpk_bf16(m2, m3);
            *(uint2*)(S + (r0 + lc) * SPAD + ct * 16 + lg * 4) = pk;
        }
        patt += __shfl_xor(patt, 16, 64); patt += __shfl_xor(patt, 32, 64);
        const float gv = (jb + r0 + lc == irel) ? 0.f : fsig(patt + attb);
        if (lg == 0) gatev[r0 + lc] = gv;

        // ---- GEMM2: E2 = C1^T @ m^T ----
        bf16x8 bg[4];
#pragma unroll
        for (int kk = 0; kk < 4; ++kk)
            bg[kk] = *(const bf16x8*)&S[(r0 + lc) * SPAD + kk * 32 + lg * 8];
        f32x4 acc2[8];
#pragma unroll
        for (int ct = 0; ct < 8; ++ct) acc2[ct] = (f32x4){0.f, 0.f, 0.f, 0.f};
        __builtin_amdgcn_s_setprio(1);
#pragma unroll
        for (int ct = 0; ct < 8; ++ct)
#pragma unroll
            for (int kk = 0; kk < 4; ++kk) {
                bf16x8 a = *(const bf16x8*)(c1p + (size_t)((ct * 4 + kk) * 64 + lane) * 8);
                acc2[ct] = __builtin_amdgcn_mfma_f32_16x16x32_bf16(a, bg[kk], acc2[ct], 0, 0, 0);
            }
        __builtin_amdgcn_s_setprio(0);

        // ---- phi[j] = sum_c silu(g_j*E2 + c1b)*c2 ----
        float pp = 0.f;
#pragma unroll
        for (int ct = 0; ct < 8; ++ct) {
            const float4 cbv = *(const float4*)(c1b + ct * 16 + lg * 4);
            const float4 cwv = *(const float4*)(c2 + ct * 16 + lg * 4);
            f32x4 a = acc2[ct];
            pp += fsilu(fmaf(gv, a[0], cbv.x)) * cwv.x + fsilu(fmaf(gv, a[1], cbv.y)) * cwv.y +
                  fsilu(fmaf(gv, a[2], cbv.z)) * cwv.z + fsilu(fmaf(gv, a[3], cbv.w)) * cwv.w;
        }
        pp += __shfl_xor(pp, 16, 64); pp += __shfl_xor(pp, 32, 64);
        if (lg == 0) phis[jb + r0 + lc] = pp;

        // ---- m_agg partial: wave's 16 rows of this half ----
#pragma unroll
        for (int q = 0; q < 16; ++q) {
            float g = gatev[r0 + q];
            unsigned u = *(const unsigned*)(S + (r0 + q) * SPAD + p * 2);
            magg0 = fmaf(g, bf2f((unsigned short)(u & 0xffffu)), magg0);
            magg1 = fmaf(g, bf2f((unsigned short)(u >> 16)), magg1);
        }
    }

    {
        float2 pr; pr.x = magg0; pr.y = magg1;
        *(float2*)(red + wv * HID + p * 2) = pr;
    }
    __syncthreads();   // B1: phis + red complete

    if (tid < NN) {
        float ph = phis[tid];
        cds[tid * 3 + 0] *= ph; cds[tid * 3 + 1] *= ph; cds[tid * 3 + 2] *= ph;
    }
    if (tid < HID)
        magg[(size_t)i * HID + tid] = red[tid] + red[HID + tid] + red[2 * HID + tid] + red[3 * HID + tid];
    __syncthreads();   // B2: cds scaled

    if (tid < 192) {
        const int a = tid >> 6, ln = tid & 63;
        float v = cds[ln * 3 + a] + cds[(ln + 64) * 3 + a];
#pragma unroll
        for (int off = 1; off <= 32; off <<= 1) v += __shfl_xor(v, off, 64);
        if (ln == 0) xdel[i * 3 + a] = v * (1.f / 127.f);
    }
}

// ---------------- node path via MFMA: 16 nodes/block, 128 blocks ----------------
__global__ __launch_bounds__(256) void k_node2(
    float* __restrict__ h, float* __restrict__ x,
    const float* __restrict__ magg, const float* __restrict__ xdel,
    const unsigned short* __restrict__ nw1p, const float* __restrict__ nb1,
    const unsigned short* __restrict__ nw2p, const float* __restrict__ nb2,
    const unsigned short* __restrict__ ewp, const float* __restrict__ eob,
    float* __restrict__ p1, float* __restrict__ p2, int last) {
    __shared__ unsigned short hm[16 * 264];   // [node][h(128)|magg(128)] bf16
    __shared__ float hf[16 * 132];            // h fp32 tile (padded)
    __shared__ unsigned short dht[16 * SPAD];
    __shared__ unsigned short hpt[16 * SPAD];

    const int n0 = blockIdx.x * 16;
    const int tid = threadIdx.x, lane = tid & 63, wv = tid >> 6;
    const int lc = lane & 15, lg = lane >> 4;

    {
        int node = tid >> 4, seg = tid & 15;
        const float* srcp = (seg < 8) ? (h + (size_t)(n0 + node) * HID + seg * 16)
                                      : (magg + (size_t)(n0 + node) * HID + (seg - 8) * 16);
        float4 v0 = ((const float4*)srcp)[0];
        float4 v1 = ((const float4*)srcp)[1];
        float4 v2 = ((const float4*)srcp)[2];
        float4 v3 = ((const float4*)srcp)[3];
        uint4 q0; q0.x = cvtpk_bf16(v0.x, v0.y); q0.y = cvtpk_bf16(v0.z, v0.w);
                  q0.z = cvtpk_bf16(v1.x, v1.y); q0.w = cvtpk_bf16(v1.z, v1.w);
        uint4 q1; q1.x = cvtpk_bf16(v2.x, v2.y); q1.y = cvtpk_bf16(v2.z, v2.w);
                  q1.z = cvtpk_bf16(v3.x, v3.y); q1.w = cvtpk_bf16(v3.z, v3.w);
        *(uint4*)&hm[node * 264 + seg * 16] = q0;
        *(uint4*)&hm[node * 264 + seg * 16 + 8] = q1;
        if (seg < 8) {
            float* dst = &hf[node * 132 + seg * 16];
            ((float4*)dst)[0] = v0; ((float4*)dst)[1] = v1;
            ((float4*)dst)[2] = v2; ((float4*)dst)[3] = v3;
        }
    }
    __syncthreads();

    // ---- stage A: dh = silu([h|magg]@nw1 + nb1) ----
    bf16x8 bb[8];
#pragma unroll
    for (int kk = 0; kk < 8; ++kk)
        bb[kk] = *(const bf16x8*)&hm[lc * 264 + kk * 32 + lg * 8];
    f32x4 da[2] = {(f32x4){0.f,0.f,0.f,0.f}, (f32x4){0.f,0.f,0.f,0.f}};
#pragma unroll
    for (int t2 = 0; t2 < 2; ++t2) {
        int ct = wv * 2 + t2;
#pragma unroll
        for (int kk = 0; kk < 8; ++kk) {
            bf16x8 a = *(const bf16x8*)(nw1p + (size_t)((ct * 8 + kk) * 64 + lane) * 8);
            da[t2] = __builtin_amdgcn_mfma_f32_16x16x32_bf16(a, bb[kk], da[t2], 0, 0, 0);
        }
    }
#pragma unroll
    for (int t2 = 0; t2 < 2; ++t2) {
        int ct = wv * 2 + t2;
        const float4 bv = *(const float4*)(nb1 + ct * 16 + lg * 4);
        float m0 = fsilu(da[t2][0] + bv.x), m1 = fsilu(da[t2][1] + bv.y);
        float m2 = fsilu(da[t2][2] + bv.z), m3 = fsilu(da[t2][3] + bv.w);
        uint2 pk; pk.x = cvtpk_bf16(m0, m1); pk.y = cvtpk_bf16(m2, m3);
        *(uint2*)&dht[lc * SPAD + ct * 16 + lg * 4] = pk;
    }
    __syncthreads();

    // ---- stage B: h' = h + dh@nw2 + nb2 ----
    bf16x8 db[4];
#pragma unroll
    for (int kk = 0; kk < 4; ++kk)
        db[kk] = *(const bf16x8*)&dht[lc * SPAD + kk * 32 + lg * 8];
    f32x4 hb[2] = {(f32x4){0.f,0.f,0.f,0.f}, (f32x4){0.f,0.f,0.f,0.f}};
#pragma unroll
    for (int t2 = 0; t2 < 2; ++t2) {
        int ct = wv * 2 + t2;
#pragma unroll
        for (int kk = 0; kk < 4; ++kk) {
            bf16x8 a = *(const bf16x8*)(nw2p + (size_t)((ct * 4 + kk) * 64 + lane) * 8);
            hb[t2] = __builtin_amdgcn_mfma_f32_16x16x32_bf16(a, db[kk], hb[t2], 0, 0, 0);
        }
    }
#pragma unroll
    for (int t2 = 0; t2 < 2; ++t2) {
        int ct = wv * 2 + t2;
        const float4 bv = *(const float4*)(nb2 + ct * 16 + lg * 4);
        const float4 hv = *(const float4*)&hf[lc * 132 + ct * 16 + lg * 4];
        float o0 = hv.x + hb[t2][0] + bv.x, o1 = hv.y + hb[t2][1] + bv.y;
        float o2 = hv.z + hb[t2][2] + bv.z, o3 = hv.w + hb[t2][3] + bv.w;
        float4 o; o.x = o0; o.y = o1; o.z = o2; o.w = o3;
        *(float4*)(h + (size_t)(n0 + lc) * HID + ct * 16 + lg * 4) = o;
        uint2 pk; pk.x = cvtpk_bf16(o0, o1); pk.y = cvtpk_bf16(o2, o3);
        *(uint2*)&hpt[lc * SPAD + ct * 16 + lg * 4] = pk;
    }
    if (tid < 48) {
        int n = tid / 3, a = tid % 3;
        x[(size_t)(n0 + n) * 3 + a] += xdel[(size_t)(n0 + n) * 3 + a];
    }
    __syncthreads();

    // ---- stage C ----
    stageC(hpt, ewp, p1, p2, eob, n0, lane, wv, last);
}

// ---------------- per-graph mean pool + head MLP ----------------
__global__ void k_poolhead(const float* __restrict__ he,
                           const float* __restrict__ w1, const float* __restrict__ b1,
                           const float* __restrict__ w2, const float* __restrict__ b2,
                           float* __restrict__ out) {
    __shared__ float hp[HID], rs[HID];
    int gph = blockIdx.x, t = threadIdx.x;
    float s = 0.f;
    for (int j = 0; j < NN; ++j) s += he[(size_t)(gph * NN + j) * HID + t];
    hp[t] = s * (1.f / 128.f);
    __syncthreads();
    float acc = b1[t];
#pragma unroll 4
    for (int k = 0; k < HID; ++k) acc += hp[k] * w1[k * HID + t];
    rs[t] = fmaxf(acc, 0.f);
    __syncthreads();
    if (t < ONF) {
        float a = b2[t];
        for (int k = 0; k < HID; ++k) a += rs[k] * w2[k * ONF + t];
        out[gph * ONF + t] = a;
    }
}

extern "C" void kernel_launch(void* const* d_in, const int* in_sizes, int n_in,
                              void* d_out, int out_size, void* d_ws, size_t ws_size,
                              hipStream_t stream) {
    const float* h0        = (const float*)d_in[0];
    const float* x0        = (const float*)d_in[1];
    const float* emb_in_w  = (const float*)d_in[2];
    const float* emb_in_b  = (const float*)d_in[3];
    const float* edge_w1   = (const float*)d_in[4];
    const float* edge_b1   = (const float*)d_in[5];
    const float* edge_w2   = (const float*)d_in[6];
    const float* edge_b2   = (const float*)d_in[7];
    const float* att_w     = (const float*)d_in[8];
    const float* att_b     = (const float*)d_in[9];
    const float* node_w1   = (const float*)d_in[10];
    const float* node_b1   = (const float*)d_in[11];
    const float* node_w2   = (const float*)d_in[12];
    const float* node_b2   = (const float*)d_in[13];
    const float* coord_w1  = (const float*)d_in[14];
    const float* coord_b1  = (const float*)d_in[15];
    const float* coord_w2  = (const float*)d_in[16];
    const float* emb_out_w = (const float*)d_in[17];
    const float* emb_out_b = (const float*)d_in[18];
    const float* head_w1   = (const float*)d_in[19];
    const float* head_b1   = (const float*)d_in[20];
    const float* head_w2   = (const float*)d_in[21];
    const float* head_b2   = (const float*)d_in[22];

    float* ws    = (float*)d_ws;
    float* h_cur = ws;                   // BN*HID
    float* p1    = h_cur + BN * HID;     // BN*HID (h_emb at the end)
    float* p2    = p1 + BN * HID;        // BN*HID
    float* magg  = p2 + BN * HID;        // BN*HID
    float* xc    = magg + BN * HID;      // BN*3
    float* xdel  = xc + BN * 3;          // BN*3
    unsigned short* wpack = (unsigned short*)(xdel + BN * 3);  // U_TOT * 8 bf16

    k_packall<<<U_TOT / 256, 256, 0, stream>>>(edge_w2, coord_w1, node_w1, edge_w1,
                                               node_w2, emb_out_w, wpack);
    k_emb0<<<BN / 16, 256, 0, stream>>>(h0, x0, emb_in_w, emb_in_b,
                                        wpack + (size_t)U_EW * 8, h_cur, xc, p1, p2);
    for (int l = 0; l < NLAY; ++l) {
        const int last = (l == NLAY - 1);
        k_edge<<<BN, 256, 0, stream>>>(xc, p1, p2,
            edge_w1 + (size_t)l * 258 * HID, edge_b1 + l * HID,
            wpack + (size_t)(U_W2 + l * 2048) * 8, edge_b2 + l * HID,
            att_w + l * HID, att_b + l,
            wpack + (size_t)(U_C1 + l * 2048) * 8, coord_b1 + l * HID, coord_w2 + l * HID,
            magg, xdel);
        k_node2<<<BN / 16, 256, 0, stream>>>(h_cur, xc, magg, xdel,
            wpack + (size_t)(U_NW1 + l * 4096) * 8, node_b1 + l * HID,
            wpack + (size_t)(U_NW2 + l * 2048) * 8, node_b2 + l * HID,
            last ? wpack + (size_t)U_EOW * 8 : wpack + (size_t)(U_EW + (l + 1) * 4096) * 8,
            emb_out_b, p1, p2, last);
    }
    k_poolhead<<<NB, HID, 0, stream>>>(p1, head_w1, head_b1, head_w2, head_b2, (float*)d_out);
}

// Round 12
// 321.465 us; speedup vs baseline: 3.7005x; 1.9571x over previous
//
#include <hip/hip_runtime.h>
#include <math.h>

#define HID 128
#define NN 128      // nodes per graph
#define NB 16       // graphs
#define BN 2048     // total nodes
#define NLAY 4
#define INF 21
#define ONF 20
#define SPAD 136    // padded LDS row stride in bf16 elems (272B: 16B-aligned, 2-way b128 — free)

// pack regions in 16B units (8 bf16 elems each)
#define U_W2   0        // 4 x 2048   (K=128, N=128)
#define U_C1   8192     // 4 x 2048
#define U_NW1  16384    // 4 x 4096   (K=256, N=128)
#define U_EW   32768    // 4 x 4096   (virtual K=128, N=256 = [ew1a|ew1b])
#define U_NW2  49152    // 4 x 2048
#define U_EOW  57344    // 1 x 2048
#define U_TOT  59392

typedef __attribute__((ext_vector_type(8))) short bf16x8;
typedef __attribute__((ext_vector_type(4))) float f32x4;

__device__ __forceinline__ float frcp(float x) {
    float r; asm("v_rcp_f32 %0, %1" : "=v"(r) : "v"(x)); return r;
}
__device__ __forceinline__ float fsilu(float v) { return v * frcp(1.f + __expf(-v)); }
__device__ __forceinline__ float fsig(float v)  { return frcp(1.f + __expf(-v)); }
__device__ __forceinline__ unsigned cvtpk_bf16(float lo, float hi) {
    unsigned r; asm("v_cvt_pk_bf16_f32 %0, %1, %2" : "=v"(r) : "v"(lo), "v"(hi)); return r;
}
__device__ __forceinline__ unsigned short f2bf(float f) {
    union { float f; unsigned u; } v; v.f = f;
    unsigned r = v.u + 0x7fffu + ((v.u >> 16) & 1u);
    return (unsigned short)(r >> 16);
}
__device__ __forceinline__ float bf2f(unsigned short u) {
    union { unsigned u; float f; } v; v.u = ((unsigned)u) << 16;
    return v.f;
}

// ---------------- pack ALL weight matrices into bf16 A-fragments of W^T ----------------
// unit u (16B = 64-lane fragment slice /8): lane l holds W[k0+j][col], j=0..7.
__global__ void k_packall(const float* __restrict__ w2, const float* __restrict__ c1,
                          const float* __restrict__ nw1, const float* __restrict__ ew1,
                          const float* __restrict__ nw2, const float* __restrict__ eow,
                          unsigned short* __restrict__ out) {
    int u = blockIdx.x * 256 + threadIdx.x;
    int l = u & 63;
    const float* src; int k0, col;
    if (u < U_C1) {                       // edge_w2, K=128
        int f = u & 2047; src = w2 + (size_t)(u >> 11) * HID * HID;
        col = (f >> 8) * 16 + (l & 15); k0 = ((f >> 6) & 3) * 32 + (l >> 4) * 8;
    } else if (u < U_NW1) {               // coord_w1, K=128
        int f = u & 2047; src = c1 + (size_t)((u - U_C1) >> 11) * HID * HID;
        col = (f >> 8) * 16 + (l & 15); k0 = ((f >> 6) & 3) * 32 + (l >> 4) * 8;
    } else if (u < U_EW) {                // node_w1, K=256
        int f = u & 4095; src = nw1 + (size_t)((u - U_NW1) >> 12) * 256 * HID;
        col = (f >> 9) * 16 + (l & 15); k0 = ((f >> 6) & 7) * 32 + (l >> 4) * 8;
    } else if (u < U_NW2) {               // edge_w1[0:256] as virtual [128 x 256]
        int f = u & 4095; src = ew1 + (size_t)((u - U_EW) >> 12) * 258 * HID;
        int c = (f >> 8) * 16 + (l & 15);             // 0..255
        col = c & 127; k0 = ((f >> 6) & 3) * 32 + (l >> 4) * 8 + (c >= 128 ? 128 : 0);
    } else if (u < U_EOW) {               // node_w2, K=128
        int f = u & 2047; src = nw2 + (size_t)((u - U_NW2) >> 11) * HID * HID;
        col = (f >> 8) * 16 + (l & 15); k0 = ((f >> 6) & 3) * 32 + (l >> 4) * 8;
    } else {                              // emb_out_w, K=128
        int f = (u - U_EOW) & 2047; src = eow;
        col = (f >> 8) * 16 + (l & 15); k0 = ((f >> 6) & 3) * 32 + (l >> 4) * 8;
    }
    unsigned short tmp[8];
#pragma unroll
    for (int j = 0; j < 8; ++j) tmp[j] = f2bf(src[(size_t)(k0 + j) * HID + col]);
    *(bf16x8*)(out + (size_t)u * 8) = *(const bf16x8*)tmp;
}

// ---------------- shared stage-C: p = h'@[ew1a|ew1b] (or h_emb = h'@eow + eob) ----------------
__device__ __forceinline__ void stageC(const unsigned short* hpt, const unsigned short* ewp,
                                       float* __restrict__ p1, float* __restrict__ p2,
                                       const float* __restrict__ eob,
                                       int n0, int lane, int wv, int last) {
    const int lc = lane & 15, lg = lane >> 4;
    bf16x8 pb[4];
#pragma unroll
    for (int kk = 0; kk < 4; ++kk)
        pb[kk] = *(const bf16x8*)&hpt[lc * SPAD + kk * 32 + lg * 8];
    if (!last) {
#pragma unroll
        for (int t4 = 0; t4 < 4; ++t4) {
            int ct = wv * 4 + t4;
            f32x4 d = (f32x4){0.f, 0.f, 0.f, 0.f};
#pragma unroll
            for (int kk = 0; kk < 4; ++kk) {
                bf16x8 a = *(const bf16x8*)(ewp + (size_t)((ct * 4 + kk) * 64 + lane) * 8);
                d = __builtin_amdgcn_mfma_f32_16x16x32_bf16(a, pb[kk], d, 0, 0, 0);
            }
            int c = ct * 16 + lg * 4;
            float* dst = (c < 128) ? (p1 + (size_t)(n0 + lc) * HID + c)
                                   : (p2 + (size_t)(n0 + lc) * HID + (c - 128));
            float4 o; o.x = d[0]; o.y = d[1]; o.z = d[2]; o.w = d[3];
            *(float4*)dst = o;
        }
    } else {
#pragma unroll
        for (int t2 = 0; t2 < 2; ++t2) {
            int ct = wv * 2 + t2;
            f32x4 d = (f32x4){0.f, 0.f, 0.f, 0.f};
#pragma unroll
            for (int kk = 0; kk < 4; ++kk) {
                bf16x8 a = *(const bf16x8*)(ewp + (size_t)((ct * 4 + kk) * 64 + lane) * 8);
                d = __builtin_amdgcn_mfma_f32_16x16x32_bf16(a, pb[kk], d, 0, 0, 0);
            }
            int c = ct * 16 + lg * 4;
            const float4 bv = *(const float4*)(eob + c);
            float4 o; o.x = d[0] + bv.x; o.y = d[1] + bv.y; o.z = d[2] + bv.z; o.w = d[3] + bv.w;
            *(float4*)(p1 + (size_t)(n0 + lc) * HID + c) = o;
        }
    }
}

// ---------------- embed + layer-0 projections (16 nodes/block, MFMA proj) ----------------
__global__ __launch_bounds__(256) void k_emb0(
    const float* __restrict__ h0, const float* __restrict__ x0,
    const float* __restrict__ wemb, const float* __restrict__ bemb,
    const unsigned short* __restrict__ ewp0,
    float* __restrict__ h, float* __restrict__ x,
    float* __restrict__ p1, float* __restrict__ p2) {
    __shared__ float hraw[16 * INF];
    __shared__ unsigned short hpt[16 * SPAD];
    const int n0 = blockIdx.x * 16;
    const int tid = threadIdx.x, lane = tid & 63, wv = tid >> 6;
    for (int t = tid; t < 16 * INF; t += 256)          // 336 > 256: strided load
        hraw[t] = h0[(size_t)n0 * INF + t];
    if (tid < 48) x[(size_t)n0 * 3 + tid] = x0[(size_t)n0 * 3 + tid];
    __syncthreads();
#pragma unroll
    for (int ot = 0; ot < 4; ++ot) {
        int idx = tid + ot * 256;          // 1024 col-pairs
        int node = idx >> 6, cp = idx & 63;
        float a0 = bemb[cp * 2], a1 = bemb[cp * 2 + 1];
#pragma unroll
        for (int k = 0; k < INF; ++k) {
            float hv = hraw[node * INF + k];
            a0 = fmaf(hv, wemb[k * HID + cp * 2], a0);
            a1 = fmaf(hv, wemb[k * HID + cp * 2 + 1], a1);
        }
        float2 o; o.x = a0; o.y = a1;
        *(float2*)(h + (size_t)(n0 + node) * HID + cp * 2) = o;
        *(unsigned*)&hpt[node * SPAD + cp * 2] = cvtpk_bf16(a0, a1);
    }
    __syncthreads();
    stageC(hpt, ewp0, p1, p2, bemb /*unused*/, n0, lane, wv, 0);
}

// ---------------- edge pipeline: one block per node i, HALF-J split ----------------
// Two halves of 64 j-rows; each wave owns 16 rows per half. S = 64 rows -> 22.3 KB LDS.
// #pragma unroll 1 on the GEMM ct loops is ESSENTIAL: a fully-unrolled ct loop lets the
// pre-RA scheduler hoist all 32 weight-fragment loads (128 VGPRs) ahead of the MFMAs ->
// demand > cap -> spill (rounds 8-11: FETCH 168-288 MB scratch traffic, invariant to cap).
// unroll 1 caps in-flight fragments at 4 (16 regs); TLP hides the exposed L2 latency.
__global__ __launch_bounds__(256, 4) void k_edge(
    const float* __restrict__ x, const float* __restrict__ p1g, const float* __restrict__ p2g,
    const float* __restrict__ ew1, const float* __restrict__ eb1,
    const unsigned short* __restrict__ w2p, const float* __restrict__ b2,
    const float* __restrict__ attw, const float* __restrict__ attbp,
    const unsigned short* __restrict__ c1p, const float* __restrict__ c1b, const float* __restrict__ c2,
    float* __restrict__ magg, float* __restrict__ xdel) {
    __shared__ unsigned short S[64 * SPAD];    // silu(pre) then m (ungated); rows wave-private
    __shared__ float cds[NN * 3];
    __shared__ float rad[NN];
    __shared__ float phis[NN];
    __shared__ float gatev[64];                // per-half gates, wave-private slices
    __shared__ float red[4 * HID];

    const int i = blockIdx.x;
    const int base = i & ~127;
    const int irel = i & 127;
    const int tid = threadIdx.x;
    const int lane = tid & 63;
    const int wv = tid >> 6;
    const int lc = lane & 15, lg = lane >> 4;
    const int r0 = wv * 16;                    // wave's local row base in S

    // ---- phase 0: coord diffs + radial (block-wide) ----
    const float xi0 = x[i * 3 + 0], xi1 = x[i * 3 + 1], xi2 = x[i * 3 + 2];
    if (tid < NN) {
        int j = base + tid;
        float d0 = xi0 - x[j * 3 + 0], d1 = xi1 - x[j * 3 + 1], d2 = xi2 - x[j * 3 + 2];
        cds[tid * 3 + 0] = d0; cds[tid * 3 + 1] = d1; cds[tid * 3 + 2] = d2;
        rad[tid] = d0 * d0 + d1 * d1 + d2 * d2;
    }
    __syncthreads();

    // hoisted S-build constants
    const int bl = lane & 31, bh = lane >> 5;
    const int col0 = bl * 4;
    const float4 wrv = *(const float4*)(ew1 + 256 * HID + col0);
    float4 bcv = *(const float4*)(ew1 + 257 * HID + col0);
    {
        const float4 p1v = *(const float4*)(p1g + (size_t)i * HID + col0);
        const float4 ebv = *(const float4*)(eb1 + col0);
        bcv.x += ebv.x + p1v.x; bcv.y += ebv.y + p1v.y;
        bcv.z += ebv.z + p1v.z; bcv.w += ebv.w + p1v.w;
    }
    const float attb = attbp[0];

    const int p = tid & 63;          // feature pair for m_agg
    float magg0 = 0.f, magg1 = 0.f;  // accumulated across halves

#pragma unroll 1
    for (int half = 0; half < 2; ++half) {
        const int jb = half * 64;

        // ---- S = silu(pre), wave-private rows [r0, r0+16) of this half ----
#pragma unroll
        for (int it = 0; it < 8; ++it) {
            int lrow = r0 + it * 2 + bh;
            int grow = jb + lrow;
            float rv = rad[grow];
            const float4 p2v = *(const float4*)(p2g + (size_t)(base + grow) * HID + col0);
            float v0 = fsilu(fmaf(rv, wrv.x, p2v.x + bcv.x));
            float v1 = fsilu(fmaf(rv, wrv.y, p2v.y + bcv.y));
            float v2 = fsilu(fmaf(rv, wrv.z, p2v.z + bcv.z));
            float v3 = fsilu(fmaf(rv, wrv.w, p2v.w + bcv.w));
            uint2 pk; pk.x = cvtpk_bf16(v0, v1); pk.y = cvtpk_bf16(v2, v3);
            *(uint2*)(S + lrow * SPAD + col0) = pk;
        }

        // ---- GEMM1: P = W2^T @ S^T (wave's 16 columns) ----
        bf16x8 bf[4];
#pragma unroll
        for (int kk = 0; kk < 4; ++kk)
            bf[kk] = *(const bf16x8*)&S[(r0 + lc) * SPAD + kk * 32 + lg * 8];
        f32x4 acc[8];
#pragma unroll
        for (int ct = 0; ct < 8; ++ct) acc[ct] = (f32x4){0.f, 0.f, 0.f, 0.f};
        __builtin_amdgcn_s_setprio(1);
#pragma unroll 1
        for (int ct = 0; ct < 8; ++ct)
#pragma unroll
            for (int kk = 0; kk < 4; ++kk) {
                bf16x8 a = *(const bf16x8*)(w2p + (size_t)((ct * 4 + kk) * 64 + lane) * 8);
                acc[ct] = __builtin_amdgcn_mfma_f32_16x16x32_bf16(a, bf[kk], acc[ct], 0, 0, 0);
            }
        __builtin_amdgcn_s_setprio(0);

        // ---- epilogue 1: m = silu(P + b2[c]) -> S (ungated); att partial ----
        float patt = 0.f;
#pragma unroll
        for (int ct = 0; ct < 8; ++ct) {
            const float4 b2v = *(const float4*)(b2 + ct * 16 + lg * 4);
            const float4 awv = *(const float4*)(attw + ct * 16 + lg * 4);
            f32x4 a = acc[ct];
            float m0 = fsilu(a[0] + b2v.x), m1 = fsilu(a[1] + b2v.y);
            float m2 = fsilu(a[2] + b2v.z), m3 = fsilu(a[3] + b2v.w);
            patt += m0 * awv.x + m1 * awv.y + m2 * awv.z + m3 * awv.w;
            uint2 pk; pk.x = cvtpk_bf16(m0, m1); pk.y = cvtpk_bf16(m2, m3);
            *(uint2*)(S + (r0 + lc) * SPAD + ct * 16 + lg * 4) = pk;
        }
        patt += __shfl_xor(patt, 16, 64); patt += __shfl_xor(patt, 32, 64);
        const float gv = (jb + r0 + lc == irel) ? 0.f : fsig(patt + attb);
        if (lg == 0) gatev[r0 + lc] = gv;

        // ---- GEMM2: E2 = C1^T @ m^T ----
        bf16x8 bg[4];
#pragma unroll
        for (int kk = 0; kk < 4; ++kk)
            bg[kk] = *(const bf16x8*)&S[(r0 + lc) * SPAD + kk * 32 + lg * 8];
        f32x4 acc2[8];
#pragma unroll
        for (int ct = 0; ct < 8; ++ct) acc2[ct] = (f32x4){0.f, 0.f, 0.f, 0.f};
        __builtin_amdgcn_s_setprio(1);
#pragma unroll 1
        for (int ct = 0; ct < 8; ++ct)
#pragma unroll
            for (int kk = 0; kk < 4; ++kk) {
                bf16x8 a = *(const bf16x8*)(c1p + (size_t)((ct * 4 + kk) * 64 + lane) * 8);
                acc2[ct] = __builtin_amdgcn_mfma_f32_16x16x32_bf16(a, bg[kk], acc2[ct], 0, 0, 0);
            }
        __builtin_amdgcn_s_setprio(0);

        // ---- phi[j] = sum_c silu(g_j*E2 + c1b)*c2 ----
        float pp = 0.f;
#pragma unroll
        for (int ct = 0; ct < 8; ++ct) {
            const float4 cbv = *(const float4*)(c1b + ct * 16 + lg * 4);
            const float4 cwv = *(const float4*)(c2 + ct * 16 + lg * 4);
            f32x4 a = acc2[ct];
            pp += fsilu(fmaf(gv, a[0], cbv.x)) * cwv.x + fsilu(fmaf(gv, a[1], cbv.y)) * cwv.y +
                  fsilu(fmaf(gv, a[2], cbv.z)) * cwv.z + fsilu(fmaf(gv, a[3], cbv.w)) * cwv.w;
        }
        pp += __shfl_xor(pp, 16, 64); pp += __shfl_xor(pp, 32, 64);
        if (lg == 0) phis[jb + r0 + lc] = pp;

        // ---- m_agg partial: wave's 16 rows of this half ----
#pragma unroll
        for (int q = 0; q < 16; ++q) {
            float g = gatev[r0 + q];
            unsigned u = *(const unsigned*)(S + (r0 + q) * SPAD + p * 2);
            magg0 = fmaf(g, bf2f((unsigned short)(u & 0xffffu)), magg0);
            magg1 = fmaf(g, bf2f((unsigned short)(u >> 16)), magg1);
        }
    }

    {
        float2 pr; pr.x = magg0; pr.y = magg1;
        *(float2*)(red + wv * HID + p * 2) = pr;
    }
    __syncthreads();   // B1: phis + red complete

    if (tid < NN) {
        float ph = phis[tid];
        cds[tid * 3 + 0] *= ph; cds[tid * 3 + 1] *= ph; cds[tid * 3 + 2] *= ph;
    }
    if (tid < HID)
        magg[(size_t)i * HID + tid] = red[tid] + red[HID + tid] + red[2 * HID + tid] + red[3 * HID + tid];
    __syncthreads();   // B2: cds scaled

    if (tid < 192) {
        const int a = tid >> 6, ln = tid & 63;
        float v = cds[ln * 3 + a] + cds[(ln + 64) * 3 + a];
#pragma unroll
        for (int off = 1; off <= 32; off <<= 1) v += __shfl_xor(v, off, 64);
        if (ln == 0) xdel[i * 3 + a] = v * (1.f / 127.f);
    }
}

// ---------------- node path via MFMA: 16 nodes/block, 128 blocks ----------------
__global__ __launch_bounds__(256) void k_node2(
    float* __restrict__ h, float* __restrict__ x,
    const float* __restrict__ magg, const float* __restrict__ xdel,
    const unsigned short* __restrict__ nw1p, const float* __restrict__ nb1,
    const unsigned short* __restrict__ nw2p, const float* __restrict__ nb2,
    const unsigned short* __restrict__ ewp, const float* __restrict__ eob,
    float* __restrict__ p1, float* __restrict__ p2, int last) {
    __shared__ unsigned short hm[16 * 264];   // [node][h(128)|magg(128)] bf16
    __shared__ float hf[16 * 132];            // h fp32 tile (padded)
    __shared__ unsigned short dht[16 * SPAD];
    __shared__ unsigned short hpt[16 * SPAD];

    const int n0 = blockIdx.x * 16;
    const int tid = threadIdx.x, lane = tid & 63, wv = tid >> 6;
    const int lc = lane & 15, lg = lane >> 4;

    {
        int node = tid >> 4, seg = tid & 15;
        const float* srcp = (seg < 8) ? (h + (size_t)(n0 + node) * HID + seg * 16)
                                      : (magg + (size_t)(n0 + node) * HID + (seg - 8) * 16);
        float4 v0 = ((const float4*)srcp)[0];
        float4 v1 = ((const float4*)srcp)[1];
        float4 v2 = ((const float4*)srcp)[2];
        float4 v3 = ((const float4*)srcp)[3];
        uint4 q0; q0.x = cvtpk_bf16(v0.x, v0.y); q0.y = cvtpk_bf16(v0.z, v0.w);
                  q0.z = cvtpk_bf16(v1.x, v1.y); q0.w = cvtpk_bf16(v1.z, v1.w);
        uint4 q1; q1.x = cvtpk_bf16(v2.x, v2.y); q1.y = cvtpk_bf16(v2.z, v2.w);
                  q1.z = cvtpk_bf16(v3.x, v3.y); q1.w = cvtpk_bf16(v3.z, v3.w);
        *(uint4*)&hm[node * 264 + seg * 16] = q0;
        *(uint4*)&hm[node * 264 + seg * 16 + 8] = q1;
        if (seg < 8) {
            float* dst = &hf[node * 132 + seg * 16];
            ((float4*)dst)[0] = v0; ((float4*)dst)[1] = v1;
            ((float4*)dst)[2] = v2; ((float4*)dst)[3] = v3;
        }
    }
    __syncthreads();

    // ---- stage A: dh = silu([h|magg]@nw1 + nb1) ----
    bf16x8 bb[8];
#pragma unroll
    for (int kk = 0; kk < 8; ++kk)
        bb[kk] = *(const bf16x8*)&hm[lc * 264 + kk * 32 + lg * 8];
    f32x4 da[2] = {(f32x4){0.f,0.f,0.f,0.f}, (f32x4){0.f,0.f,0.f,0.f}};
#pragma unroll
    for (int t2 = 0; t2 < 2; ++t2) {
        int ct = wv * 2 + t2;
#pragma unroll
        for (int kk = 0; kk < 8; ++kk) {
            bf16x8 a = *(const bf16x8*)(nw1p + (size_t)((ct * 8 + kk) * 64 + lane) * 8);
            da[t2] = __builtin_amdgcn_mfma_f32_16x16x32_bf16(a, bb[kk], da[t2], 0, 0, 0);
        }
    }
#pragma unroll
    for (int t2 = 0; t2 < 2; ++t2) {
        int ct = wv * 2 + t2;
        const float4 bv = *(const float4*)(nb1 + ct * 16 + lg * 4);
        float m0 = fsilu(da[t2][0] + bv.x), m1 = fsilu(da[t2][1] + bv.y);
        float m2 = fsilu(da[t2][2] + bv.z), m3 = fsilu(da[t2][3] + bv.w);
        uint2 pk; pk.x = cvtpk_bf16(m0, m1); pk.y = cvtpk_bf16(m2, m3);
        *(uint2*)&dht[lc * SPAD + ct * 16 + lg * 4] = pk;
    }
    __syncthreads();

    // ---- stage B: h' = h + dh@nw2 + nb2 ----
    bf16x8 db[4];
#pragma unroll
    for (int kk = 0; kk < 4; ++kk)
        db[kk] = *(const bf16x8*)&dht[lc * SPAD + kk * 32 + lg * 8];
    f32x4 hb[2] = {(f32x4){0.f,0.f,0.f,0.f}, (f32x4){0.f,0.f,0.f,0.f}};
#pragma unroll
    for (int t2 = 0; t2 < 2; ++t2) {
        int ct = wv * 2 + t2;
#pragma unroll
        for (int kk = 0; kk < 4; ++kk) {
            bf16x8 a = *(const bf16x8*)(nw2p + (size_t)((ct * 4 + kk) * 64 + lane) * 8);
            hb[t2] = __builtin_amdgcn_mfma_f32_16x16x32_bf16(a, db[kk], hb[t2], 0, 0, 0);
        }
    }
#pragma unroll
    for (int t2 = 0; t2 < 2; ++t2) {
        int ct = wv * 2 + t2;
        const float4 bv = *(const float4*)(nb2 + ct * 16 + lg * 4);
        const float4 hv = *(const float4*)&hf[lc * 132 + ct * 16 + lg * 4];
        float o0 = hv.x + hb[t2][0] + bv.x, o1 = hv.y + hb[t2][1] + bv.y;
        float o2 = hv.z + hb[t2][2] + bv.z, o3 = hv.w + hb[t2][3] + bv.w;
        float4 o; o.x = o0; o.y = o1; o.z = o2; o.w = o3;
        *(float4*)(h + (size_t)(n0 + lc) * HID + ct * 16 + lg * 4) = o;
        uint2 pk; pk.x = cvtpk_bf16(o0, o1); pk.y = cvtpk_bf16(o2, o3);
        *(uint2*)&hpt[lc * SPAD + ct * 16 + lg * 4] = pk;
    }
    if (tid < 48) {
        int n = tid / 3, a = tid % 3;
        x[(size_t)(n0 + n) * 3 + a] += xdel[(size_t)(n0 + n) * 3 + a];
    }
    __syncthreads();

    // ---- stage C ----
    stageC(hpt, ewp, p1, p2, eob, n0, lane, wv, last);
}

// ---------------- per-graph mean pool + head MLP ----------------
__global__ void k_poolhead(const float* __restrict__ he,
                           const float* __restrict__ w1, const float* __restrict__ b1,
                           const float* __restrict__ w2, const float* __restrict__ b2,
                           float* __restrict__ out) {
    __shared__ float hp[HID], rs[HID];
    int gph = blockIdx.x, t = threadIdx.x;
    float s = 0.f;
    for (int j = 0; j < NN; ++j) s += he[(size_t)(gph * NN + j) * HID + t];
    hp[t] = s * (1.f / 128.f);
    __syncthreads();
    float acc = b1[t];
#pragma unroll 4
    for (int k = 0; k < HID; ++k) acc += hp[k] * w1[k * HID + t];
    rs[t] = fmaxf(acc, 0.f);
    __syncthreads();
    if (t < ONF) {
        float a = b2[t];
        for (int k = 0; k < HID; ++k) a += rs[k] * w2[k * ONF + t];
        out[gph * ONF + t] = a;
    }
}

extern "C" void kernel_launch(void* const* d_in, const int* in_sizes, int n_in,
                              void* d_out, int out_size, void* d_ws, size_t ws_size,
                              hipStream_t stream) {
    const float* h0        = (const float*)d_in[0];
    const float* x0        = (const float*)d_in[1];
    const float* emb_in_w  = (const float*)d_in[2];
    const float* emb_in_b  = (const float*)d_in[3];
    const float* edge_w1   = (const float*)d_in[4];
    const float* edge_b1   = (const float*)d_in[5];
    const float* edge_w2   = (const float*)d_in[6];
    const float* edge_b2   = (const float*)d_in[7];
    const float* att_w     = (const float*)d_in[8];
    const float* att_b     = (const float*)d_in[9];
    const float* node_w1   = (const float*)d_in[10];
    const float* node_b1   = (const float*)d_in[11];
    const float* node_w2   = (const float*)d_in[12];
    const float* node_b2   = (const float*)d_in[13];
    const float* coord_w1  = (const float*)d_in[14];
    const float* coord_b1  = (const float*)d_in[15];
    const float* coord_w2  = (const float*)d_in[16];
    const float* emb_out_w = (const float*)d_in[17];
    const float* emb_out_b = (const float*)d_in[18];
    const float* head_w1   = (const float*)d_in[19];
    const float* head_b1   = (const float*)d_in[20];
    const float* head_w2   = (const float*)d_in[21];
    const float* head_b2   = (const float*)d_in[22];

    float* ws    = (float*)d_ws;
    float* h_cur = ws;                   // BN*HID
    float* p1    = h_cur + BN * HID;     // BN*HID (h_emb at the end)
    float* p2    = p1 + BN * HID;        // BN*HID
    float* magg  = p2 + BN * HID;        // BN*HID
    float* xc    = magg + BN * HID;      // BN*3
    float* xdel  = xc + BN * 3;          // BN*3
    unsigned short* wpack = (unsigned short*)(xdel + BN * 3);  // U_TOT * 8 bf16

    k_packall<<<U_TOT / 256, 256, 0, stream>>>(edge_w2, coord_w1, node_w1, edge_w1,
                                               node_w2, emb_out_w, wpack);
    k_emb0<<<BN / 16, 256, 0, stream>>>(h0, x0, emb_in_w, emb_in_b,
                                        wpack + (size_t)U_EW * 8, h_cur, xc, p1, p2);
    for (int l = 0; l < NLAY; ++l) {
        const int last = (l == NLAY - 1);
        k_edge<<<BN, 256, 0, stream>>>(xc, p1, p2,
            edge_w1 + (size_t)l * 258 * HID, edge_b1 + l * HID,
            wpack + (size_t)(U_W2 + l * 2048) * 8, edge_b2 + l * HID,
            att_w + l * HID, att_b + l,
            wpack + (size_t)(U_C1 + l * 2048) * 8, coord_b1 + l * HID, coord_w2 + l * HID,
            magg, xdel);
        k_node2<<<BN / 16, 256, 0, stream>>>(h_cur, xc, magg, xdel,
            wpack + (size_t)(U_NW1 + l * 4096) * 8, node_b1 + l * HID,
            wpack + (size_t)(U_NW2 + l * 2048) * 8, node_b2 + l * HID,
            last ? wpack + (size_t)U_EOW * 8 : wpack + (size_t)(U_EW + (l + 1) * 4096) * 8,
            emb_out_b, p1, p2, last);
    }
    k_poolhead<<<NB, HID, 0, stream>>>(p1, head_w1, head_b1, head_w2, head_b2, (float*)d_out);
}

// Round 13
// 231.402 us; speedup vs baseline: 5.1408x; 1.3892x over previous
//
#include <hip/hip_runtime.h>
#include <math.h>

#define HID 128
#define NN 128      // nodes per graph
#define NB 16       // graphs
#define BN 2048     // total nodes
#define NLAY 4
#define INF 21
#define ONF 20
#define SPAD 136    // padded LDS row stride in bf16 elems

// pack regions in 16B units (8 bf16 elems each)
#define U_W2   0        // 4 x 2048   (K=128, N=128)
#define U_C1   8192     // 4 x 2048
#define U_NW1  16384    // 4 x 4096   (K=256, N=128)
#define U_EW   32768    // 4 x 4096   (virtual K=128, N=256 = [ew1a|ew1b])
#define U_NW2  49152    // 4 x 2048
#define U_EOW  57344    // 1 x 2048
#define U_TOT  59392

typedef __attribute__((ext_vector_type(8))) short bf16x8;
typedef __attribute__((ext_vector_type(4))) float f32x4;

__device__ __forceinline__ float frcp(float x) {
    float r; asm("v_rcp_f32 %0, %1" : "=v"(r) : "v"(x)); return r;
}
__device__ __forceinline__ float fsilu(float v) { return v * frcp(1.f + __expf(-v)); }
__device__ __forceinline__ float fsig(float v)  { return frcp(1.f + __expf(-v)); }
__device__ __forceinline__ unsigned cvtpk_bf16(float lo, float hi) {
    unsigned r; asm("v_cvt_pk_bf16_f32 %0, %1, %2" : "=v"(r) : "v"(lo), "v"(hi)); return r;
}
__device__ __forceinline__ unsigned short f2bf(float f) {
    union { float f; unsigned u; } v; v.f = f;
    unsigned r = v.u + 0x7fffu + ((v.u >> 16) & 1u);
    return (unsigned short)(r >> 16);
}
__device__ __forceinline__ float bf2f(unsigned short u) {
    union { unsigned u; float f; } v; v.u = ((unsigned)u) << 16;
    return v.f;
}

// ---------------- pack ALL weight matrices into bf16 A-fragments of W^T ----------------
__global__ void k_packall(const float* __restrict__ w2, const float* __restrict__ c1,
                          const float* __restrict__ nw1, const float* __restrict__ ew1,
                          const float* __restrict__ nw2, const float* __restrict__ eow,
                          unsigned short* __restrict__ out) {
    int u = blockIdx.x * 256 + threadIdx.x;
    int l = u & 63;
    const float* src; int k0, col;
    if (u < U_C1) {                       // edge_w2, K=128
        int f = u & 2047; src = w2 + (size_t)(u >> 11) * HID * HID;
        col = (f >> 8) * 16 + (l & 15); k0 = ((f >> 6) & 3) * 32 + (l >> 4) * 8;
    } else if (u < U_NW1) {               // coord_w1, K=128
        int f = u & 2047; src = c1 + (size_t)((u - U_C1) >> 11) * HID * HID;
        col = (f >> 8) * 16 + (l & 15); k0 = ((f >> 6) & 3) * 32 + (l >> 4) * 8;
    } else if (u < U_EW) {                // node_w1, K=256
        int f = u & 4095; src = nw1 + (size_t)((u - U_NW1) >> 12) * 256 * HID;
        col = (f >> 9) * 16 + (l & 15); k0 = ((f >> 6) & 7) * 32 + (l >> 4) * 8;
    } else if (u < U_NW2) {               // edge_w1[0:256] as virtual [128 x 256]
        int f = u & 4095; src = ew1 + (size_t)((u - U_EW) >> 12) * 258 * HID;
        int c = (f >> 8) * 16 + (l & 15);             // 0..255
        col = c & 127; k0 = ((f >> 6) & 3) * 32 + (l >> 4) * 8 + (c >= 128 ? 128 : 0);
    } else if (u < U_EOW) {               // node_w2, K=128
        int f = u & 2047; src = nw2 + (size_t)((u - U_NW2) >> 11) * HID * HID;
        col = (f >> 8) * 16 + (l & 15); k0 = ((f >> 6) & 3) * 32 + (l >> 4) * 8;
    } else {                              // emb_out_w, K=128
        int f = (u - U_EOW) & 2047; src = eow;
        col = (f >> 8) * 16 + (l & 15); k0 = ((f >> 6) & 3) * 32 + (l >> 4) * 8;
    }
    unsigned short tmp[8];
#pragma unroll
    for (int j = 0; j < 8; ++j) tmp[j] = f2bf(src[(size_t)(k0 + j) * HID + col]);
    *(bf16x8*)(out + (size_t)u * 8) = *(const bf16x8*)tmp;
}

// ---------------- shared stage-C: p = h'@[ew1a|ew1b] (or h_emb = h'@eow + eob) ----------------
__device__ __forceinline__ void stageC(const unsigned short* hpt, const unsigned short* ewp,
                                       float* __restrict__ p1, float* __restrict__ p2,
                                       const float* __restrict__ eob,
                                       int n0, int lane, int wv, int last) {
    const int lc = lane & 15, lg = lane >> 4;
    bf16x8 pb[4];
#pragma unroll
    for (int kk = 0; kk < 4; ++kk)
        pb[kk] = *(const bf16x8*)&hpt[lc * SPAD + kk * 32 + lg * 8];
    if (!last) {
#pragma unroll
        for (int t4 = 0; t4 < 4; ++t4) {
            int ct = wv * 4 + t4;
            f32x4 d = (f32x4){0.f, 0.f, 0.f, 0.f};
#pragma unroll
            for (int kk = 0; kk < 4; ++kk) {
                bf16x8 a = *(const bf16x8*)(ewp + (size_t)((ct * 4 + kk) * 64 + lane) * 8);
                d = __builtin_amdgcn_mfma_f32_16x16x32_bf16(a, pb[kk], d, 0, 0, 0);
            }
            int c = ct * 16 + lg * 4;
            float* dst = (c < 128) ? (p1 + (size_t)(n0 + lc) * HID + c)
                                   : (p2 + (size_t)(n0 + lc) * HID + (c - 128));
            float4 o; o.x = d[0]; o.y = d[1]; o.z = d[2]; o.w = d[3];
            *(float4*)dst = o;
        }
    } else {
#pragma unroll
        for (int t2 = 0; t2 < 2; ++t2) {
            int ct = wv * 2 + t2;
            f32x4 d = (f32x4){0.f, 0.f, 0.f, 0.f};
#pragma unroll
            for (int kk = 0; kk < 4; ++kk) {
                bf16x8 a = *(const bf16x8*)(ewp + (size_t)((ct * 4 + kk) * 64 + lane) * 8);
                d = __builtin_amdgcn_mfma_f32_16x16x32_bf16(a, pb[kk], d, 0, 0, 0);
            }
            int c = ct * 16 + lg * 4;
            const float4 bv = *(const float4*)(eob + c);
            float4 o; o.x = d[0] + bv.x; o.y = d[1] + bv.y; o.z = d[2] + bv.z; o.w = d[3] + bv.w;
            *(float4*)(p1 + (size_t)(n0 + lc) * HID + c) = o;
        }
    }
}

// ---------------- embed + layer-0 projections (16 nodes/block, MFMA proj) ----------------
__global__ __launch_bounds__(256) void k_emb0(
    const float* __restrict__ h0, const float* __restrict__ x0,
    const float* __restrict__ wemb, const float* __restrict__ bemb,
    const unsigned short* __restrict__ ewp0,
    float* __restrict__ h, float* __restrict__ x,
    float* __restrict__ p1, float* __restrict__ p2) {
    __shared__ float hraw[16 * INF];
    __shared__ unsigned short hpt[16 * SPAD];
    const int n0 = blockIdx.x * 16;
    const int tid = threadIdx.x, lane = tid & 63, wv = tid >> 6;
    for (int t = tid; t < 16 * INF; t += 256)          // 336 > 256: strided load
        hraw[t] = h0[(size_t)n0 * INF + t];
    if (tid < 48) x[(size_t)n0 * 3 + tid] = x0[(size_t)n0 * 3 + tid];
    __syncthreads();
#pragma unroll
    for (int ot = 0; ot < 4; ++ot) {
        int idx = tid + ot * 256;          // 1024 col-pairs
        int node = idx >> 6, cp = idx & 63;
        float a0 = bemb[cp * 2], a1 = bemb[cp * 2 + 1];
#pragma unroll
        for (int k = 0; k < INF; ++k) {
            float hv = hraw[node * INF + k];
            a0 = fmaf(hv, wemb[k * HID + cp * 2], a0);
            a1 = fmaf(hv, wemb[k * HID + cp * 2 + 1], a1);
        }
        float2 o; o.x = a0; o.y = a1;
        *(float2*)(h + (size_t)(n0 + node) * HID + cp * 2) = o;
        *(unsigned*)&hpt[node * SPAD + cp * 2] = cvtpk_bf16(a0, a1);
    }
    __syncthreads();
    stageC(hpt, ewp0, p1, p2, bemb /*unused*/, n0, lane, wv, 0);
}

// ---------------- edge pipeline (round-7 structure): one block per node i ----------------
// Full 128-row S, wave owns 32 rows (2 jt), acc[8][2] = 64 AGPR + 64 arch = exactly 128:
// fits launch_bounds(256,4) with no spill (r7 measured). Occupancy arc r8-r12 proved this
// structure is at its register-shaped ceiling; do not shrink acc or serialize ct loops.
__global__ __launch_bounds__(256, 4) void k_edge(
    const float* __restrict__ x, const float* __restrict__ p1g, const float* __restrict__ p2g,
    const float* __restrict__ ew1, const float* __restrict__ eb1,
    const unsigned short* __restrict__ w2p, const float* __restrict__ b2,
    const float* __restrict__ attw, const float* __restrict__ attbp,
    const unsigned short* __restrict__ c1p, const float* __restrict__ c1b, const float* __restrict__ c2,
    float* __restrict__ magg, float* __restrict__ xdel) {
    __shared__ unsigned short S[128 * SPAD];   // silu(pre) then m (ungated), bf16; rows wave-private
    __shared__ float cds[NN * 3];
    __shared__ float rad[NN];
    __shared__ float phis[NN];
    __shared__ float gatev[NN];
    __shared__ float red[4 * HID];

    const int i = blockIdx.x;
    const int base = i & ~127;
    const int irel = i & 127;
    const int tid = threadIdx.x;
    const int lane = tid & 63;
    const int wv = tid >> 6;
    const int lc = lane & 15, lg = lane >> 4;
    const int j0 = wv * 32;

    const float xi0 = x[i * 3 + 0], xi1 = x[i * 3 + 1], xi2 = x[i * 3 + 2];
    if (tid < NN) {
        int j = base + tid;
        float d0 = xi0 - x[j * 3 + 0], d1 = xi1 - x[j * 3 + 1], d2 = xi2 - x[j * 3 + 2];
        cds[tid * 3 + 0] = d0; cds[tid * 3 + 1] = d1; cds[tid * 3 + 2] = d2;
        rad[tid] = d0 * d0 + d1 * d1 + d2 * d2;
    }
    __syncthreads();

    // ---- S = silu(pre), wave-private rows ----
    {
        const int bl = lane & 31, bh = lane >> 5;
        const int col0 = bl * 4;
        const float4 p1v = *(const float4*)(p1g + (size_t)i * HID + col0);
        const float4 wrv = *(const float4*)(ew1 + 256 * HID + col0);
        float4 bcv = *(const float4*)(ew1 + 257 * HID + col0);
        const float4 ebv = *(const float4*)(eb1 + col0);
        bcv.x += ebv.x + p1v.x; bcv.y += ebv.y + p1v.y;
        bcv.z += ebv.z + p1v.z; bcv.w += ebv.w + p1v.w;
#pragma unroll
        for (int it = 0; it < 16; ++it) {
            int row = j0 + it * 2 + bh;
            float rv = rad[row];
            const float4 p2v = *(const float4*)(p2g + (size_t)(base + row) * HID + col0);
            float v0 = fsilu(fmaf(rv, wrv.x, p2v.x + bcv.x));
            float v1 = fsilu(fmaf(rv, wrv.y, p2v.y + bcv.y));
            float v2 = fsilu(fmaf(rv, wrv.z, p2v.z + bcv.z));
            float v3 = fsilu(fmaf(rv, wrv.w, p2v.w + bcv.w));
            uint2 pk; pk.x = cvtpk_bf16(v0, v1); pk.y = cvtpk_bf16(v2, v3);
            *(uint2*)(S + row * SPAD + col0) = pk;
        }
    }

    // ---- GEMM1: P = W2^T @ S^T ----
    bf16x8 bf[4][2];
#pragma unroll
    for (int kk = 0; kk < 4; ++kk)
#pragma unroll
        for (int jt = 0; jt < 2; ++jt)
            bf[kk][jt] = *(const bf16x8*)&S[(j0 + jt * 16 + lc) * SPAD + kk * 32 + lg * 8];
    f32x4 acc[8][2];
#pragma unroll
    for (int ct = 0; ct < 8; ++ct) { acc[ct][0] = (f32x4){0.f,0.f,0.f,0.f}; acc[ct][1] = (f32x4){0.f,0.f,0.f,0.f}; }
    __builtin_amdgcn_s_setprio(1);
#pragma unroll
    for (int ct = 0; ct < 8; ++ct)
#pragma unroll
        for (int kk = 0; kk < 4; ++kk) {
            bf16x8 a = *(const bf16x8*)(w2p + (size_t)((ct * 4 + kk) * 64 + lane) * 8);
            acc[ct][0] = __builtin_amdgcn_mfma_f32_16x16x32_bf16(a, bf[kk][0], acc[ct][0], 0, 0, 0);
            acc[ct][1] = __builtin_amdgcn_mfma_f32_16x16x32_bf16(a, bf[kk][1], acc[ct][1], 0, 0, 0);
        }
    __builtin_amdgcn_s_setprio(0);

    // ---- epilogue 1: m = silu(P + b2[c]) -> S (ungated); att partials ----
    float patt0 = 0.f, patt1 = 0.f;
#pragma unroll
    for (int ct = 0; ct < 8; ++ct) {
        const float4 b2v = *(const float4*)(b2 + ct * 16 + lg * 4);
        const float4 awv = *(const float4*)(attw + ct * 16 + lg * 4);
        {
            f32x4 a = acc[ct][0];
            float m0 = fsilu(a[0] + b2v.x), m1 = fsilu(a[1] + b2v.y);
            float m2 = fsilu(a[2] + b2v.z), m3 = fsilu(a[3] + b2v.w);
            patt0 += m0 * awv.x + m1 * awv.y + m2 * awv.z + m3 * awv.w;
            uint2 pk; pk.x = cvtpk_bf16(m0, m1); pk.y = cvtpk_bf16(m2, m3);
            *(uint2*)(S + (j0 + lc) * SPAD + ct * 16 + lg * 4) = pk;
        }
        {
            f32x4 a = acc[ct][1];
            float m0 = fsilu(a[0] + b2v.x), m1 = fsilu(a[1] + b2v.y);
            float m2 = fsilu(a[2] + b2v.z), m3 = fsilu(a[3] + b2v.w);
            patt1 += m0 * awv.x + m1 * awv.y + m2 * awv.z + m3 * awv.w;
            uint2 pk; pk.x = cvtpk_bf16(m0, m1); pk.y = cvtpk_bf16(m2, m3);
            *(uint2*)(S + (j0 + 16 + lc) * SPAD + ct * 16 + lg * 4) = pk;
        }
    }
    patt0 += __shfl_xor(patt0, 16, 64); patt0 += __shfl_xor(patt0, 32, 64);
    patt1 += __shfl_xor(patt1, 16, 64); patt1 += __shfl_xor(patt1, 32, 64);
    const float attb = attbp[0];
    const float gv0 = (j0 + lc == irel) ? 0.f : fsig(patt0 + attb);
    const float gv1 = (j0 + 16 + lc == irel) ? 0.f : fsig(patt1 + attb);
    if (lg == 0) {
        gatev[j0 + lc] = gv0;
        gatev[j0 + 16 + lc] = gv1;
    }

    // ---- GEMM2: E2 = C1^T @ m^T (gate applied afterwards) ----
    bf16x8 bg[4][2];
#pragma unroll
    for (int kk = 0; kk < 4; ++kk)
#pragma unroll
        for (int jt = 0; jt < 2; ++jt)
            bg[kk][jt] = *(const bf16x8*)&S[(j0 + jt * 16 + lc) * SPAD + kk * 32 + lg * 8];
    f32x4 acc2[8][2];
#pragma unroll
    for (int ct = 0; ct < 8; ++ct) { acc2[ct][0] = (f32x4){0.f,0.f,0.f,0.f}; acc2[ct][1] = (f32x4){0.f,0.f,0.f,0.f}; }
    __builtin_amdgcn_s_setprio(1);
#pragma unroll
    for (int ct = 0; ct < 8; ++ct)
#pragma unroll
        for (int kk = 0; kk < 4; ++kk) {
            bf16x8 a = *(const bf16x8*)(c1p + (size_t)((ct * 4 + kk) * 64 + lane) * 8);
            acc2[ct][0] = __builtin_amdgcn_mfma_f32_16x16x32_bf16(a, bg[kk][0], acc2[ct][0], 0, 0, 0);
            acc2[ct][1] = __builtin_amdgcn_mfma_f32_16x16x32_bf16(a, bg[kk][1], acc2[ct][1], 0, 0, 0);
        }
    __builtin_amdgcn_s_setprio(0);

    // ---- phi[j] = sum_c silu(g_j*E2 + c1b)*c2 ----
    float pp0 = 0.f, pp1 = 0.f;
#pragma unroll
    for (int ct = 0; ct < 8; ++ct) {
        const float4 cbv = *(const float4*)(c1b + ct * 16 + lg * 4);
        const float4 cwv = *(const float4*)(c2 + ct * 16 + lg * 4);
        {
            f32x4 a = acc2[ct][0];
            pp0 += fsilu(fmaf(gv0, a[0], cbv.x)) * cwv.x + fsilu(fmaf(gv0, a[1], cbv.y)) * cwv.y +
                   fsilu(fmaf(gv0, a[2], cbv.z)) * cwv.z + fsilu(fmaf(gv0, a[3], cbv.w)) * cwv.w;
        }
        {
            f32x4 a = acc2[ct][1];
            pp1 += fsilu(fmaf(gv1, a[0], cbv.x)) * cwv.x + fsilu(fmaf(gv1, a[1], cbv.y)) * cwv.y +
                   fsilu(fmaf(gv1, a[2], cbv.z)) * cwv.z + fsilu(fmaf(gv1, a[3], cbv.w)) * cwv.w;
        }
    }
    pp0 += __shfl_xor(pp0, 16, 64); pp0 += __shfl_xor(pp0, 32, 64);
    pp1 += __shfl_xor(pp1, 16, 64); pp1 += __shfl_xor(pp1, 32, 64);
    if (lg == 0) {
        phis[j0 + lc] = pp0;
        phis[j0 + 16 + lc] = pp1;
    }

    // ---- m_agg: vectorized gated column-sum over wave's 32 rows ----
    // lane (lg,lc): features lc*8..lc*8+7 (one b128), rows j0+q*4+lg, q=0..7.
    // Replaces r7's 64x scalar-u32 loop (~380 VALU + 128 LDS ops -> ~150 VALU + 16 LDS).
    {
        float macc[8] = {0.f, 0.f, 0.f, 0.f, 0.f, 0.f, 0.f, 0.f};
#pragma unroll
        for (int q = 0; q < 8; ++q) {
            int row = j0 + q * 4 + lg;
            float g = gatev[row];                                   // broadcast within 16-lane group
            bf16x8 v = *(const bf16x8*)&S[row * SPAD + lc * 8];
#pragma unroll
            for (int e = 0; e < 8; ++e)
                macc[e] = fmaf(g, bf2f((unsigned short)v[e]), macc[e]);
        }
#pragma unroll
        for (int e = 0; e < 8; ++e) {                               // reduce over lg (rows)
            macc[e] += __shfl_xor(macc[e], 16, 64);
            macc[e] += __shfl_xor(macc[e], 32, 64);
        }
        if (lg == 0) {
            float4 a; a.x = macc[0]; a.y = macc[1]; a.z = macc[2]; a.w = macc[3];
            float4 b; b.x = macc[4]; b.y = macc[5]; b.z = macc[6]; b.w = macc[7];
            *(float4*)(red + wv * HID + lc * 8) = a;
            *(float4*)(red + wv * HID + lc * 8 + 4) = b;
        }
    }
    __syncthreads();   // B1: phis + red complete

    if (tid < NN) {
        float ph = phis[tid];
        cds[tid * 3 + 0] *= ph; cds[tid * 3 + 1] *= ph; cds[tid * 3 + 2] *= ph;
    }
    if (tid < HID)
        magg[(size_t)i * HID + tid] = red[tid] + red[HID + tid] + red[2 * HID + tid] + red[3 * HID + tid];
    __syncthreads();   // B2: cds scaled

    if (tid < 192) {
        const int a = tid >> 6, ln = tid & 63;
        float v = cds[ln * 3 + a] + cds[(ln + 64) * 3 + a];
#pragma unroll
        for (int off = 1; off <= 32; off <<= 1) v += __shfl_xor(v, off, 64);
        if (ln == 0) xdel[i * 3 + a] = v * (1.f / 127.f);
    }
}

// ---------------- node path via MFMA: 16 nodes/block, 128 blocks ----------------
__global__ __launch_bounds__(256) void k_node2(
    float* __restrict__ h, float* __restrict__ x,
    const float* __restrict__ magg, const float* __restrict__ xdel,
    const unsigned short* __restrict__ nw1p, const float* __restrict__ nb1,
    const unsigned short* __restrict__ nw2p, const float* __restrict__ nb2,
    const unsigned short* __restrict__ ewp, const float* __restrict__ eob,
    float* __restrict__ p1, float* __restrict__ p2, int last) {
    __shared__ unsigned short hm[16 * 264];   // [node][h(128)|magg(128)] bf16
    __shared__ float hf[16 * 132];            // h fp32 tile (padded)
    __shared__ unsigned short dht[16 * SPAD];
    __shared__ unsigned short hpt[16 * SPAD];

    const int n0 = blockIdx.x * 16;
    const int tid = threadIdx.x, lane = tid & 63, wv = tid >> 6;
    const int lc = lane & 15, lg = lane >> 4;

    {
        int node = tid >> 4, seg = tid & 15;
        const float* srcp = (seg < 8) ? (h + (size_t)(n0 + node) * HID + seg * 16)
                                      : (magg + (size_t)(n0 + node) * HID + (seg - 8) * 16);
        float4 v0 = ((const float4*)srcp)[0];
        float4 v1 = ((const float4*)srcp)[1];
        float4 v2 = ((const float4*)srcp)[2];
        float4 v3 = ((const float4*)srcp)[3];
        uint4 q0; q0.x = cvtpk_bf16(v0.x, v0.y); q0.y = cvtpk_bf16(v0.z, v0.w);
                  q0.z = cvtpk_bf16(v1.x, v1.y); q0.w = cvtpk_bf16(v1.z, v1.w);
        uint4 q1; q1.x = cvtpk_bf16(v2.x, v2.y); q1.y = cvtpk_bf16(v2.z, v2.w);
                  q1.z = cvtpk_bf16(v3.x, v3.y); q1.w = cvtpk_bf16(v3.z, v3.w);
        *(uint4*)&hm[node * 264 + seg * 16] = q0;
        *(uint4*)&hm[node * 264 + seg * 16 + 8] = q1;
        if (seg < 8) {
            float* dst = &hf[node * 132 + seg * 16];
            ((float4*)dst)[0] = v0; ((float4*)dst)[1] = v1;
            ((float4*)dst)[2] = v2; ((float4*)dst)[3] = v3;
        }
    }
    __syncthreads();

    // ---- stage A: dh = silu([h|magg]@nw1 + nb1) ----
    bf16x8 bb[8];
#pragma unroll
    for (int kk = 0; kk < 8; ++kk)
        bb[kk] = *(const bf16x8*)&hm[lc * 264 + kk * 32 + lg * 8];
    f32x4 da[2] = {(f32x4){0.f,0.f,0.f,0.f}, (f32x4){0.f,0.f,0.f,0.f}};
#pragma unroll
    for (int t2 = 0; t2 < 2; ++t2) {
        int ct = wv * 2 + t2;
#pragma unroll
        for (int kk = 0; kk < 8; ++kk) {
            bf16x8 a = *(const bf16x8*)(nw1p + (size_t)((ct * 8 + kk) * 64 + lane) * 8);
            da[t2] = __builtin_amdgcn_mfma_f32_16x16x32_bf16(a, bb[kk], da[t2], 0, 0, 0);
        }
    }
#pragma unroll
    for (int t2 = 0; t2 < 2; ++t2) {
        int ct = wv * 2 + t2;
        const float4 bv = *(const float4*)(nb1 + ct * 16 + lg * 4);
        float m0 = fsilu(da[t2][0] + bv.x), m1 = fsilu(da[t2][1] + bv.y);
        float m2 = fsilu(da[t2][2] + bv.z), m3 = fsilu(da[t2][3] + bv.w);
        uint2 pk; pk.x = cvtpk_bf16(m0, m1); pk.y = cvtpk_bf16(m2, m3);
        *(uint2*)&dht[lc * SPAD + ct * 16 + lg * 4] = pk;
    }
    __syncthreads();

    // ---- stage B: h' = h + dh@nw2 + nb2 ----
    bf16x8 db[4];
#pragma unroll
    for (int kk = 0; kk < 4; ++kk)
        db[kk] = *(const bf16x8*)&dht[lc * SPAD + kk * 32 + lg * 8];
    f32x4 hb[2] = {(f32x4){0.f,0.f,0.f,0.f}, (f32x4){0.f,0.f,0.f,0.f}};
#pragma unroll
    for (int t2 = 0; t2 < 2; ++t2) {
        int ct = wv * 2 + t2;
#pragma unroll
        for (int kk = 0; kk < 4; ++kk) {
            bf16x8 a = *(const bf16x8*)(nw2p + (size_t)((ct * 4 + kk) * 64 + lane) * 8);
            hb[t2] = __builtin_amdgcn_mfma_f32_16x16x32_bf16(a, db[kk], hb[t2], 0, 0, 0);
        }
    }
#pragma unroll
    for (int t2 = 0; t2 < 2; ++t2) {
        int ct = wv * 2 + t2;
        const float4 bv = *(const float4*)(nb2 + ct * 16 + lg * 4);
        const float4 hv = *(const float4*)&hf[lc * 132 + ct * 16 + lg * 4];
        float o0 = hv.x + hb[t2][0] + bv.x, o1 = hv.y + hb[t2][1] + bv.y;
        float o2 = hv.z + hb[t2][2] + bv.z, o3 = hv.w + hb[t2][3] + bv.w;
        float4 o; o.x = o0; o.y = o1; o.z = o2; o.w = o3;
        *(float4*)(h + (size_t)(n0 + lc) * HID + ct * 16 + lg * 4) = o;
        uint2 pk; pk.x = cvtpk_bf16(o0, o1); pk.y = cvtpk_bf16(o2, o3);
        *(uint2*)&hpt[lc * SPAD + ct * 16 + lg * 4] = pk;
    }
    if (tid < 48) {
        int n = tid / 3, a = tid % 3;
        x[(size_t)(n0 + n) * 3 + a] += xdel[(size_t)(n0 + n) * 3 + a];
    }
    __syncthreads();

    // ---- stage C ----
    stageC(hpt, ewp, p1, p2, eob, n0, lane, wv, last);
}

// ---------------- per-graph mean pool + head MLP ----------------
__global__ void k_poolhead(const float* __restrict__ he,
                           const float* __restrict__ w1, const float* __restrict__ b1,
                           const float* __restrict__ w2, const float* __restrict__ b2,
                           float* __restrict__ out) {
    __shared__ float hp[HID], rs[HID];
    int gph = blockIdx.x, t = threadIdx.x;
    float s = 0.f;
    for (int j = 0; j < NN; ++j) s += he[(size_t)(gph * NN + j) * HID + t];
    hp[t] = s * (1.f / 128.f);
    __syncthreads();
    float acc = b1[t];
#pragma unroll 4
    for (int k = 0; k < HID; ++k) acc += hp[k] * w1[k * HID + t];
    rs[t] = fmaxf(acc, 0.f);
    __syncthreads();
    if (t < ONF) {
        float a = b2[t];
        for (int k = 0; k < HID; ++k) a += rs[k] * w2[k * ONF + t];
        out[gph * ONF + t] = a;
    }
}

extern "C" void kernel_launch(void* const* d_in, const int* in_sizes, int n_in,
                              void* d_out, int out_size, void* d_ws, size_t ws_size,
                              hipStream_t stream) {
    const float* h0        = (const float*)d_in[0];
    const float* x0        = (const float*)d_in[1];
    const float* emb_in_w  = (const float*)d_in[2];
    const float* emb_in_b  = (const float*)d_in[3];
    const float* edge_w1   = (const float*)d_in[4];
    const float* edge_b1   = (const float*)d_in[5];
    const float* edge_w2   = (const float*)d_in[6];
    const float* edge_b2   = (const float*)d_in[7];
    const float* att_w     = (const float*)d_in[8];
    const float* att_b     = (const float*)d_in[9];
    const float* node_w1   = (const float*)d_in[10];
    const float* node_b1   = (const float*)d_in[11];
    const float* node_w2   = (const float*)d_in[12];
    const float* node_b2   = (const float*)d_in[13];
    const float* coord_w1  = (const float*)d_in[14];
    const float* coord_b1  = (const float*)d_in[15];
    const float* coord_w2  = (const float*)d_in[16];
    const float* emb_out_w = (const float*)d_in[17];
    const float* emb_out_b = (const float*)d_in[18];
    const float* head_w1   = (const float*)d_in[19];
    const float* head_b1   = (const float*)d_in[20];
    const float* head_w2   = (const float*)d_in[21];
    const float* head_b2   = (const float*)d_in[22];

    float* ws    = (float*)d_ws;
    float* h_cur = ws;                   // BN*HID
    float* p1    = h_cur + BN * HID;     // BN*HID (h_emb at the end)
    float* p2    = p1 + BN * HID;        // BN*HID
    float* magg  = p2 + BN * HID;        // BN*HID
    float* xc    = magg + BN * HID;      // BN*3
    float* xdel  = xc + BN * 3;          // BN*3
    unsigned short* wpack = (unsigned short*)(xdel + BN * 3);  // U_TOT * 8 bf16

    k_packall<<<U_TOT / 256, 256, 0, stream>>>(edge_w2, coord_w1, node_w1, edge_w1,
                                               node_w2, emb_out_w, wpack);
    k_emb0<<<BN / 16, 256, 0, stream>>>(h0, x0, emb_in_w, emb_in_b,
                                        wpack + (size_t)U_EW * 8, h_cur, xc, p1, p2);
    for (int l = 0; l < NLAY; ++l) {
        const int last = (l == NLAY - 1);
        k_edge<<<BN, 256, 0, stream>>>(xc, p1, p2,
            edge_w1 + (size_t)l * 258 * HID, edge_b1 + l * HID,
            wpack + (size_t)(U_W2 + l * 2048) * 8, edge_b2 + l * HID,
            att_w + l * HID, att_b + l,
            wpack + (size_t)(U_C1 + l * 2048) * 8, coord_b1 + l * HID, coord_w2 + l * HID,
            magg, xdel);
        k_node2<<<BN / 16, 256, 0, stream>>>(h_cur, xc, magg, xdel,
            wpack + (size_t)(U_NW1 + l * 4096) * 8, node_b1 + l * HID,
            wpack + (size_t)(U_NW2 + l * 2048) * 8, node_b2 + l * HID,
            last ? wpack + (size_t)U_EOW * 8 : wpack + (size_t)(U_EW + (l + 1) * 4096) * 8,
            emb_out_b, p1, p2, last);
    }
    k_poolhead<<<NB, HID, 0, stream>>>(p1, head_w1, head_b1, head_w2, head_b2, (float*)d_out);
}